// Round 1
// baseline (210.512 us; speedup 1.0000x reference)
//
#include <hip/hip_runtime.h>
#include <hip/hip_bf16.h>

// CantorMultiheadFusion: x -> QKV proj -> sliding-window(K=64, clipped) MHA -> out proj (+bias)
// B=2 S=2048 DIM=1024 H=16 D=64 K=64
//
// Pipeline:
//  1) cvt: f32 -> bf16 for x, [Wq;Wk;Wv] (as 3072x1024), Wo
//  2) gemm_nt<0>: qkv[4096][3072] (bf16) = x_bf16 @ Wqkv^T  (NT: both operands K-contiguous)
//  3) attn: per-(b,s,h) wave: 64 clipped-window scores, softmax, PV -> attn_out bf16
//  4) gemm_nt<1>: out[4096][1024] (f32) = attn_out @ Wo^T + bo

typedef __attribute__((ext_vector_type(8))) short bf16x8;
typedef __attribute__((ext_vector_type(4))) float f32x4;

__device__ __forceinline__ unsigned short f32_to_bf16_rne(float f) {
    unsigned u = __float_as_uint(f);
    u += 0x7FFFu + ((u >> 16) & 1u);
    return (unsigned short)(u >> 16);
}
__device__ __forceinline__ float bf16_to_f32(unsigned short s) {
    return __uint_as_float(((unsigned)s) << 16);
}

// ---------------- conversion kernel: 4 floats / thread ----------------
__global__ __launch_bounds__(256) void cvt_f32_to_bf16(
    const float4* __restrict__ in, ushort4* __restrict__ out, int n4) {
    int i = blockIdx.x * 256 + threadIdx.x;
    if (i >= n4) return;
    float4 v = in[i];
    ushort4 o;
    o.x = f32_to_bf16_rne(v.x);
    o.y = f32_to_bf16_rne(v.y);
    o.z = f32_to_bf16_rne(v.z);
    o.w = f32_to_bf16_rne(v.w);
    out[i] = o;
}

// ---------------- NT GEMM: C[M][N] = A[M][K] * B[N][K]^T ----------------
// 128x128 tile, BK=32, 256 threads = 4 waves (2x2), each wave 64x64 via 4x4
// fragments of mfma_f32_16x16x32_bf16. global_load_lds width-16 staging.
// WRITE_MODE 0: bf16 store (ushort). WRITE_MODE 1: f32 store + bias.
template<int WRITE_MODE>
__global__ __launch_bounds__(256) void gemm_nt(
    const ushort* __restrict__ A, const ushort* __restrict__ B,
    void* __restrict__ Cout, const float* __restrict__ bias,
    int M, int N, int K, int ldc) {
    __shared__ ushort As[128 * 32];
    __shared__ ushort Bs[128 * 32];

    const int t    = threadIdx.x;
    const int lane = t & 63;
    const int wid  = t >> 6;
    const int wr   = wid >> 1;   // wave row 0..1
    const int wc   = wid & 1;    // wave col 0..1
    const int mBase = blockIdx.y * 128;
    const int nBase = blockIdx.x * 128;

    f32x4 acc[4][4] = {};

    // staging map: thread t covers 16B at LDS byte offset t*16 (per half-tile)
    const int ar = t >> 2;          // row within 64-row half tile
    const int ac = (t & 3) * 8;     // k-element offset (8 bf16 = 16B)
    const ushort* Aptr = A + (size_t)(mBase + ar) * K + ac;
    const ushort* Bptr = B + (size_t)(nBase + ar) * K + ac;
    ushort* AsW = As + t * 8;       // t*16 bytes
    ushort* BsW = Bs + t * 8;

    // fragment read addresses (LDS linear [128][32] ushort)
    const int kg = (lane >> 4) * 8;       // k group offset
    const int rA = wr * 64 + (lane & 15); // A row within tile
    const int rB = wc * 64 + (lane & 15); // B row (== C col) within tile

    for (int kt = 0; kt < K; kt += 32) {
        __syncthreads();
        __builtin_amdgcn_global_load_lds(
            (const __attribute__((address_space(1))) void*)(Aptr + kt),
            (__attribute__((address_space(3))) void*)AsW, 16, 0, 0);
        __builtin_amdgcn_global_load_lds(
            (const __attribute__((address_space(1))) void*)(Aptr + (size_t)64 * K + kt),
            (__attribute__((address_space(3))) void*)(AsW + 64 * 32), 16, 0, 0);
        __builtin_amdgcn_global_load_lds(
            (const __attribute__((address_space(1))) void*)(Bptr + kt),
            (__attribute__((address_space(3))) void*)BsW, 16, 0, 0);
        __builtin_amdgcn_global_load_lds(
            (const __attribute__((address_space(1))) void*)(Bptr + (size_t)64 * K + kt),
            (__attribute__((address_space(3))) void*)(BsW + 64 * 32), 16, 0, 0);
        __syncthreads();

        bf16x8 af[4], bfr[4];
#pragma unroll
        for (int m = 0; m < 4; ++m)
            af[m] = *reinterpret_cast<const bf16x8*>(&As[(rA + m * 16) * 32 + kg]);
#pragma unroll
        for (int n = 0; n < 4; ++n)
            bfr[n] = *reinterpret_cast<const bf16x8*>(&Bs[(rB + n * 16) * 32 + kg]);
#pragma unroll
        for (int m = 0; m < 4; ++m)
#pragma unroll
            for (int n = 0; n < 4; ++n)
                acc[m][n] = __builtin_amdgcn_mfma_f32_16x16x32_bf16(
                    af[m], bfr[n], acc[m][n], 0, 0, 0);
    }

    // epilogue: C/D layout col=lane&15, row=(lane>>4)*4+reg  [m89-verified]
    const int crow0 = mBase + wr * 64 + (lane >> 4) * 4;
    const int ccol0 = nBase + wc * 64 + (lane & 15);
#pragma unroll
    for (int m = 0; m < 4; ++m) {
#pragma unroll
        for (int n = 0; n < 4; ++n) {
            const int col = ccol0 + n * 16;
#pragma unroll
            for (int r = 0; r < 4; ++r) {
                const int row = crow0 + m * 16 + r;
                const float val = acc[m][n][r];
                if (WRITE_MODE == 0) {
                    ((ushort*)Cout)[(size_t)row * ldc + col] = f32_to_bf16_rne(val);
                } else {
                    ((float*)Cout)[(size_t)row * ldc + col] = val + bias[col];
                }
            }
        }
    }
}

// ---------------- sliding-window attention ----------------
// One wave per (b,s,h). Lane j: score_j = q . k[clip(s-32+j)] * 0.125
// (clip duplicates edge keys exactly like the reference's routes gather).
// 64-lane shfl softmax; then lane d accumulates out[d] = sum_j p_j * v_j[d].
__global__ __launch_bounds__(256) void attn_kernel(
    const ushort* __restrict__ qkv,   // [4096][3072] bf16: q|k|v blocks of 1024
    ushort* __restrict__ attn_out) {  // [4096][1024] bf16
    const int lane = threadIdx.x & 63;
    const int wib  = threadIdx.x >> 6;
    const int gw   = blockIdx.x * 4 + wib;   // 0..65535
    const int h = gw & 15;
    const int s = (gw >> 4) & 2047;
    const int b = gw >> 15;
    const int row = b * 2048 + s;

    const ushort* qrow = qkv + (size_t)row * 3072 + h * 64;
    int kj = s - 32 + lane;
    kj = min(max(kj, 0), 2047);
    const ushort* krow = qkv + (size_t)(b * 2048 + kj) * 3072 + 1024 + h * 64;

    float score = 0.f;
#pragma unroll
    for (int c = 0; c < 8; ++c) {
        bf16x8 qv = *reinterpret_cast<const bf16x8*>(qrow + c * 8);
        bf16x8 kv = *reinterpret_cast<const bf16x8*>(krow + c * 8);
#pragma unroll
        for (int i = 0; i < 8; ++i)
            score += bf16_to_f32((unsigned short)qv[i]) * bf16_to_f32((unsigned short)kv[i]);
    }
    score *= 0.125f;  // 1/sqrt(64)

    // softmax over 64 lanes
    float mx = score;
#pragma unroll
    for (int off = 32; off; off >>= 1) mx = fmaxf(mx, __shfl_xor(mx, off));
    float p = __expf(score - mx);
    float sum = p;
#pragma unroll
    for (int off = 32; off; off >>= 1) sum += __shfl_xor(sum, off);
    p /= sum;

    __shared__ float p_lds[4][64];
    p_lds[wib][lane] = p;
    __syncthreads();

    // PV: lane == d
    float acc = 0.f;
    const ushort* vbase = qkv + (size_t)b * 2048 * 3072 + 2048 + h * 64 + lane;
#pragma unroll 8
    for (int j = 0; j < 64; ++j) {
        int rj = s - 32 + j;
        rj = min(max(rj, 0), 2047);
        acc += p_lds[wib][j] * bf16_to_f32(vbase[(size_t)rj * 3072]);
    }
    attn_out[(size_t)row * 1024 + h * 64 + lane] = f32_to_bf16_rne(acc);
}

// ---------------- launch ----------------
extern "C" void kernel_launch(void* const* d_in, const int* in_sizes, int n_in,
                              void* d_out, int out_size, void* d_ws, size_t ws_size,
                              hipStream_t stream) {
    const float* x  = (const float*)d_in[0];
    // d_in[1] = cantor_coords — unused by the reference
    const float* Wq = (const float*)d_in[2];
    const float* Wk = (const float*)d_in[3];
    const float* Wv = (const float*)d_in[4];
    const float* Wo = (const float*)d_in[5];
    const float* bo = (const float*)d_in[6];

    const int M = 4096;          // B*S
    const int DIM = 1024;

    // workspace layout (ushort elements): 48 MB total
    ushort* xb   = (ushort*)d_ws;                 // 4096*1024
    ushort* Wqkv = xb + (size_t)M * DIM;          // 3072*1024
    ushort* Wob  = Wqkv + (size_t)3072 * 1024;    // 1024*1024
    ushort* qkv  = Wob + (size_t)1024 * 1024;     // 4096*3072
    ushort* attn = qkv + (size_t)M * 3072;        // 4096*1024

    // conversions
    cvt_f32_to_bf16<<<(M * DIM / 4 + 255) / 256, 256, 0, stream>>>(
        (const float4*)x, (ushort4*)xb, M * DIM / 4);
    cvt_f32_to_bf16<<<(DIM * DIM / 4 + 255) / 256, 256, 0, stream>>>(
        (const float4*)Wq, (ushort4*)Wqkv, DIM * DIM / 4);
    cvt_f32_to_bf16<<<(DIM * DIM / 4 + 255) / 256, 256, 0, stream>>>(
        (const float4*)Wk, (ushort4*)(Wqkv + (size_t)DIM * DIM), DIM * DIM / 4);
    cvt_f32_to_bf16<<<(DIM * DIM / 4 + 255) / 256, 256, 0, stream>>>(
        (const float4*)Wv, (ushort4*)(Wqkv + (size_t)2 * DIM * DIM), DIM * DIM / 4);
    cvt_f32_to_bf16<<<(DIM * DIM / 4 + 255) / 256, 256, 0, stream>>>(
        (const float4*)Wo, (ushort4*)Wob, DIM * DIM / 4);

    // qkv = x @ [Wq;Wk;Wv]^T  -> bf16
    gemm_nt<0><<<dim3(3072 / 128, M / 128), 256, 0, stream>>>(
        xb, Wqkv, (void*)qkv, nullptr, M, 3072, DIM, 3072);

    // sliding-window attention
    attn_kernel<<<(2 * 2048 * 16) / 4, 256, 0, stream>>>(qkv, attn);

    // out = attn @ Wo^T + bo -> f32
    gemm_nt<1><<<dim3(DIM / 128, M / 128), 256, 0, stream>>>(
        attn, Wob, d_out, bo, M, DIM, DIM, DIM);
}

// Round 2
// 118.487 us; speedup vs baseline: 1.7767x; 1.7767x over previous
//
#include <hip/hip_runtime.h>
#include <hip/hip_bf16.h>

// CantorMultiheadFusion: x -> QKV proj -> sliding-window(K=64, clipped) MHA -> out proj (+bias)
// B=2 S=2048 DIM=1024 H=16 D=64 K=64
//
// Pipeline:
//  1) cvt: f32 -> bf16 for x, [Wq;Wk;Wv] (3072x1024), Wo
//  2) gemm_nt<0>: qkv[4096][3072] bf16 = x @ Wqkv^T
//  3) transpose_v: Vt[b][h][64][2048] bf16 (aliased over dead xb region)
//  4) attn_band: interior rows [64,1984) via MFMA banded attention
//     attn_edge: rows [0,64)+[1984,2048) via exact clipped-window VALU kernel
//  5) gemm_nt<1>: out[4096][1024] f32 = attn @ Wo^T + bo

typedef __attribute__((ext_vector_type(8))) short bf16x8;
typedef __attribute__((ext_vector_type(4))) float f32x4;

__device__ __forceinline__ unsigned short f32_to_bf16_rne(float f) {
    unsigned u = __float_as_uint(f);
    u += 0x7FFFu + ((u >> 16) & 1u);
    return (unsigned short)(u >> 16);
}
__device__ __forceinline__ float bf16_to_f32(unsigned short s) {
    return __uint_as_float(((unsigned)s) << 16);
}

// ---------------- conversion kernel ----------------
__global__ __launch_bounds__(256) void cvt_f32_to_bf16(
    const float4* __restrict__ in, ushort4* __restrict__ out, int n4) {
    int i = blockIdx.x * 256 + threadIdx.x;
    if (i >= n4) return;
    float4 v = in[i];
    ushort4 o;
    o.x = f32_to_bf16_rne(v.x);
    o.y = f32_to_bf16_rne(v.y);
    o.z = f32_to_bf16_rne(v.z);
    o.w = f32_to_bf16_rne(v.w);
    out[i] = o;
}

// ---------------- NT GEMM: C[M][N] = A[M][K] * B[N][K]^T ----------------
template<int WRITE_MODE>
__global__ __launch_bounds__(256) void gemm_nt(
    const ushort* __restrict__ A, const ushort* __restrict__ B,
    void* __restrict__ Cout, const float* __restrict__ bias,
    int M, int N, int K, int ldc) {
    __shared__ ushort As[128 * 32];
    __shared__ ushort Bs[128 * 32];

    const int t    = threadIdx.x;
    const int lane = t & 63;
    const int wid  = t >> 6;
    const int wr   = wid >> 1;
    const int wc   = wid & 1;
    const int mBase = blockIdx.y * 128;
    const int nBase = blockIdx.x * 128;

    f32x4 acc[4][4] = {};

    const int ar = t >> 2;
    const int ac = (t & 3) * 8;
    const ushort* Aptr = A + (size_t)(mBase + ar) * K + ac;
    const ushort* Bptr = B + (size_t)(nBase + ar) * K + ac;
    ushort* AsW = As + t * 8;
    ushort* BsW = Bs + t * 8;

    const int kg = (lane >> 4) * 8;
    const int rA = wr * 64 + (lane & 15);
    const int rB = wc * 64 + (lane & 15);

    for (int kt = 0; kt < K; kt += 32) {
        __syncthreads();
        __builtin_amdgcn_global_load_lds(
            (const __attribute__((address_space(1))) void*)(Aptr + kt),
            (__attribute__((address_space(3))) void*)AsW, 16, 0, 0);
        __builtin_amdgcn_global_load_lds(
            (const __attribute__((address_space(1))) void*)(Aptr + (size_t)64 * K + kt),
            (__attribute__((address_space(3))) void*)(AsW + 64 * 32), 16, 0, 0);
        __builtin_amdgcn_global_load_lds(
            (const __attribute__((address_space(1))) void*)(Bptr + kt),
            (__attribute__((address_space(3))) void*)BsW, 16, 0, 0);
        __builtin_amdgcn_global_load_lds(
            (const __attribute__((address_space(1))) void*)(Bptr + (size_t)64 * K + kt),
            (__attribute__((address_space(3))) void*)(BsW + 64 * 32), 16, 0, 0);
        __syncthreads();

        bf16x8 af[4], bfr[4];
#pragma unroll
        for (int m = 0; m < 4; ++m)
            af[m] = *reinterpret_cast<const bf16x8*>(&As[(rA + m * 16) * 32 + kg]);
#pragma unroll
        for (int n = 0; n < 4; ++n)
            bfr[n] = *reinterpret_cast<const bf16x8*>(&Bs[(rB + n * 16) * 32 + kg]);
#pragma unroll
        for (int m = 0; m < 4; ++m)
#pragma unroll
            for (int n = 0; n < 4; ++n)
                acc[m][n] = __builtin_amdgcn_mfma_f32_16x16x32_bf16(
                    af[m], bfr[n], acc[m][n], 0, 0, 0);
    }

    const int crow0 = mBase + wr * 64 + (lane >> 4) * 4;
    const int ccol0 = nBase + wc * 64 + (lane & 15);
#pragma unroll
    for (int m = 0; m < 4; ++m) {
#pragma unroll
        for (int n = 0; n < 4; ++n) {
            const int col = ccol0 + n * 16;
#pragma unroll
            for (int r = 0; r < 4; ++r) {
                const int row = crow0 + m * 16 + r;
                const float val = acc[m][n][r];
                if (WRITE_MODE == 0) {
                    ((ushort*)Cout)[(size_t)row * ldc + col] = f32_to_bf16_rne(val);
                } else {
                    ((float*)Cout)[(size_t)row * ldc + col] = val + bias[col];
                }
            }
        }
    }
}

// ---------------- V transpose: qkv V-part -> Vt[b][h][64][2048] ----------------
__global__ __launch_bounds__(256) void transpose_v(
    const ushort* __restrict__ qkv, ushort* __restrict__ Vt) {
    const int unit = blockIdx.x;       // 2*16*32 = 1024
    const int st = unit & 31;          // chunk of 64 s-rows
    const int h  = (unit >> 5) & 15;
    const int b  = unit >> 9;
    __shared__ ushort tile[64][72];
    const int t = threadIdx.x;

    const int r0 = t >> 3;
    const int c0 = (t & 7) * 8;
#pragma unroll
    for (int i = 0; i < 2; ++i) {
        const int r = r0 + i * 32;
        bf16x8 v = *reinterpret_cast<const bf16x8*>(
            qkv + ((size_t)(b * 2048 + st * 64 + r)) * 3072 + 2048 + h * 64 + c0);
#pragma unroll
        for (int j = 0; j < 4; ++j) {
            // 8B-aligned writes (row stride 144B is 8B-multiple)
            ((uint*)&tile[r][c0])[j] = ((uint)(unsigned short)v[2 * j]) |
                                       (((uint)(unsigned short)v[2 * j + 1]) << 16);
        }
    }
    __syncthreads();

    const int d = t & 63, sg = t >> 6;
#pragma unroll
    for (int i = 0; i < 2; ++i) {
        const int s0 = sg * 16 + i * 8;
        ushort4 lo, hi;
        lo.x = tile[s0 + 0][d]; lo.y = tile[s0 + 1][d];
        lo.z = tile[s0 + 2][d]; lo.w = tile[s0 + 3][d];
        hi.x = tile[s0 + 4][d]; hi.y = tile[s0 + 5][d];
        hi.z = tile[s0 + 6][d]; hi.w = tile[s0 + 7][d];
        ushort* dst = Vt + (((size_t)(b * 16 + h) * 64 + d) * 2048) + st * 64 + s0;
        *reinterpret_cast<ushort4*>(dst) = lo;
        *reinterpret_cast<ushort4*>(dst + 4) = hi;
    }
}

// ---------------- interior banded MFMA attention ----------------
// One wave per (b,h,32-row q-block qs in [64,1984)). K window = [qs-32, qs+63] (96 rows).
// S^T = K*Q^T (swapped -> lane&15 = q row), band mask qi<=ki<=qi+63, softmax via
// 4-lane-group shfl_xor(16/32), P through padded LDS, PV = P*V with Vt rows as B-frag.
#define PADW 104
__global__ __launch_bounds__(64) void attn_band(
    const ushort* __restrict__ qkv, const ushort* __restrict__ Vt,
    ushort* __restrict__ attn_out) {
    const int lane = threadIdx.x;
    const int unit = blockIdx.x;       // 0..1919
    const int qb = unit % 60;
    const int h  = (unit / 60) & 15;
    const int b  = unit / 960;
    const int qs = 64 + qb * 32;
    const int kstart = qs - 32;
    const int c15 = lane & 15, g = lane >> 4;

    __shared__ ushort P_lds[32 * PADW];

    // ---- QK^T: accS[kt][qt], D row-dim = ki, col = qi ----
    const ushort* Qbase = qkv + (size_t)(b * 2048 + qs) * 3072 + h * 64;
    const ushort* Kbase = qkv + (size_t)(b * 2048 + kstart) * 3072 + 1024 + h * 64;

    bf16x8 qf[2][2];
#pragma unroll
    for (int qt = 0; qt < 2; ++qt)
#pragma unroll
        for (int dc = 0; dc < 2; ++dc)
            qf[qt][dc] = *reinterpret_cast<const bf16x8*>(
                Qbase + (size_t)(qt * 16 + c15) * 3072 + dc * 32 + g * 8);

    f32x4 accS[6][2] = {};
#pragma unroll
    for (int kt = 0; kt < 6; ++kt) {
#pragma unroll
        for (int dc = 0; dc < 2; ++dc) {
            bf16x8 kf = *reinterpret_cast<const bf16x8*>(
                Kbase + (size_t)(kt * 16 + c15) * 3072 + dc * 32 + g * 8);
#pragma unroll
            for (int qt = 0; qt < 2; ++qt)
                accS[kt][qt] = __builtin_amdgcn_mfma_f32_16x16x32_bf16(
                    kf, qf[qt][dc], accS[kt][qt], 0, 0, 0);
        }
    }

    // ---- masked softmax (per q row; lane&15 = qi, 4-lane group over ki) ----
    float mx[2] = {-1e30f, -1e30f};
#pragma unroll
    for (int kt = 0; kt < 6; ++kt)
#pragma unroll
        for (int qt = 0; qt < 2; ++qt)
#pragma unroll
            for (int r = 0; r < 4; ++r) {
                const int ki = kt * 16 + g * 4 + r;
                const int qi = qt * 16 + c15;
                if (ki >= qi && ki <= qi + 63)
                    mx[qt] = fmaxf(mx[qt], accS[kt][qt][r] * 0.125f);
            }
#pragma unroll
    for (int qt = 0; qt < 2; ++qt) {
        mx[qt] = fmaxf(mx[qt], __shfl_xor(mx[qt], 16));
        mx[qt] = fmaxf(mx[qt], __shfl_xor(mx[qt], 32));
    }
    float sum[2] = {0.f, 0.f};
#pragma unroll
    for (int kt = 0; kt < 6; ++kt)
#pragma unroll
        for (int qt = 0; qt < 2; ++qt)
#pragma unroll
            for (int r = 0; r < 4; ++r) {
                const int ki = kt * 16 + g * 4 + r;
                const int qi = qt * 16 + c15;
                float p = 0.f;
                if (ki >= qi && ki <= qi + 63)
                    p = __expf(accS[kt][qt][r] * 0.125f - mx[qt]);
                accS[kt][qt][r] = p;
                sum[qt] += p;
            }
#pragma unroll
    for (int qt = 0; qt < 2; ++qt) {
        sum[qt] += __shfl_xor(sum[qt], 16);
        sum[qt] += __shfl_xor(sum[qt], 32);
        sum[qt] = 1.f / sum[qt];
    }
#pragma unroll
    for (int kt = 0; kt < 6; ++kt)
#pragma unroll
        for (int qt = 0; qt < 2; ++qt)
#pragma unroll
            for (int r = 0; r < 4; ++r) {
                const int ki = kt * 16 + g * 4 + r;
                const int qi = qt * 16 + c15;
                P_lds[qi * PADW + ki] = f32_to_bf16_rne(accS[kt][qt][r] * sum[qt]);
            }

    // ---- PV: out[qi][d] = P(32x96) @ V(96x64), V read from Vt rows ----
    const ushort* VtBase = Vt + ((size_t)(b * 16 + h) * 64) * 2048 + kstart;
    f32x4 accO[2][4] = {};
#pragma unroll
    for (int u = 0; u < 3; ++u) {
        bf16x8 pf[2];
#pragma unroll
        for (int qt = 0; qt < 2; ++qt)
            pf[qt] = *reinterpret_cast<const bf16x8*>(
                &P_lds[(qt * 16 + c15) * PADW + u * 32 + g * 8]);
#pragma unroll
        for (int dt = 0; dt < 4; ++dt) {
            bf16x8 vf = *reinterpret_cast<const bf16x8*>(
                VtBase + (size_t)(dt * 16 + c15) * 2048 + u * 32 + g * 8);
#pragma unroll
            for (int qt = 0; qt < 2; ++qt)
                accO[qt][dt] = __builtin_amdgcn_mfma_f32_16x16x32_bf16(
                    pf[qt], vf, accO[qt][dt], 0, 0, 0);
        }
    }

    // ---- store: row = qs + qt*16 + g*4 + r, col = h*64 + dt*16 + c15 ----
#pragma unroll
    for (int qt = 0; qt < 2; ++qt)
#pragma unroll
        for (int dt = 0; dt < 4; ++dt)
#pragma unroll
            for (int r = 0; r < 4; ++r) {
                const int row = b * 2048 + qs + qt * 16 + g * 4 + r;
                const int col = h * 64 + dt * 16 + c15;
                attn_out[(size_t)row * 1024 + col] = f32_to_bf16_rne(accO[qt][dt][r]);
            }
}

// ---------------- edge attention (exact clipped-window semantics) ----------------
__global__ __launch_bounds__(256) void attn_edge(
    const ushort* __restrict__ qkv, ushort* __restrict__ attn_out) {
    const int lane = threadIdx.x & 63;
    const int wib  = threadIdx.x >> 6;
    const int gw   = blockIdx.x * 4 + wib;   // 0..4095
    const int e = gw & 127;
    const int h = (gw >> 7) & 15;
    const int b = gw >> 11;
    const int s = (e < 64) ? e : (1984 + (e - 64));
    const int row = b * 2048 + s;

    const ushort* qrow = qkv + (size_t)row * 3072 + h * 64;
    int kj = s - 32 + lane;
    kj = min(max(kj, 0), 2047);
    const ushort* krow = qkv + (size_t)(b * 2048 + kj) * 3072 + 1024 + h * 64;

    float score = 0.f;
#pragma unroll
    for (int c = 0; c < 8; ++c) {
        bf16x8 qv = *reinterpret_cast<const bf16x8*>(qrow + c * 8);
        bf16x8 kv = *reinterpret_cast<const bf16x8*>(krow + c * 8);
#pragma unroll
        for (int i = 0; i < 8; ++i)
            score += bf16_to_f32((unsigned short)qv[i]) * bf16_to_f32((unsigned short)kv[i]);
    }
    score *= 0.125f;

    float mxv = score;
#pragma unroll
    for (int off = 32; off; off >>= 1) mxv = fmaxf(mxv, __shfl_xor(mxv, off));
    float p = __expf(score - mxv);
    float sumv = p;
#pragma unroll
    for (int off = 32; off; off >>= 1) sumv += __shfl_xor(sumv, off);
    p /= sumv;

    __shared__ float p_lds[4][64];
    p_lds[wib][lane] = p;
    __syncthreads();

    float acc = 0.f;
    const ushort* vbase = qkv + (size_t)b * 2048 * 3072 + 2048 + h * 64 + lane;
#pragma unroll 8
    for (int j = 0; j < 64; ++j) {
        int rj = s - 32 + j;
        rj = min(max(rj, 0), 2047);
        acc += p_lds[wib][j] * bf16_to_f32(vbase[(size_t)rj * 3072]);
    }
    attn_out[(size_t)row * 1024 + h * 64 + lane] = f32_to_bf16_rne(acc);
}

// ---------------- launch ----------------
extern "C" void kernel_launch(void* const* d_in, const int* in_sizes, int n_in,
                              void* d_out, int out_size, void* d_ws, size_t ws_size,
                              hipStream_t stream) {
    const float* x  = (const float*)d_in[0];
    const float* Wq = (const float*)d_in[2];
    const float* Wk = (const float*)d_in[3];
    const float* Wv = (const float*)d_in[4];
    const float* Wo = (const float*)d_in[5];
    const float* bo = (const float*)d_in[6];

    const int M = 4096;
    const int DIM = 1024;

    ushort* xb   = (ushort*)d_ws;                 // 4096*1024 (reused as Vt after gemm1)
    ushort* Wqkv = xb + (size_t)M * DIM;          // 3072*1024
    ushort* Wob  = Wqkv + (size_t)3072 * 1024;    // 1024*1024
    ushort* qkv  = Wob + (size_t)1024 * 1024;     // 4096*3072
    ushort* attn = qkv + (size_t)M * 3072;        // 4096*1024
    ushort* Vt   = xb;                            // alias: xb dead after gemm1

    cvt_f32_to_bf16<<<(M * DIM / 4 + 255) / 256, 256, 0, stream>>>(
        (const float4*)x, (ushort4*)xb, M * DIM / 4);
    cvt_f32_to_bf16<<<(DIM * DIM / 4 + 255) / 256, 256, 0, stream>>>(
        (const float4*)Wq, (ushort4*)Wqkv, DIM * DIM / 4);
    cvt_f32_to_bf16<<<(DIM * DIM / 4 + 255) / 256, 256, 0, stream>>>(
        (const float4*)Wk, (ushort4*)(Wqkv + (size_t)DIM * DIM), DIM * DIM / 4);
    cvt_f32_to_bf16<<<(DIM * DIM / 4 + 255) / 256, 256, 0, stream>>>(
        (const float4*)Wv, (ushort4*)(Wqkv + (size_t)2 * DIM * DIM), DIM * DIM / 4);
    cvt_f32_to_bf16<<<(DIM * DIM / 4 + 255) / 256, 256, 0, stream>>>(
        (const float4*)Wo, (ushort4*)Wob, DIM * DIM / 4);

    gemm_nt<0><<<dim3(3072 / 128, M / 128), 256, 0, stream>>>(
        xb, Wqkv, (void*)qkv, nullptr, M, 3072, DIM, 3072);

    transpose_v<<<1024, 256, 0, stream>>>(qkv, Vt);
    attn_band<<<1920, 64, 0, stream>>>(qkv, Vt, attn);
    attn_edge<<<1024, 256, 0, stream>>>(qkv, attn);

    gemm_nt<1><<<dim3(DIM / 128, M / 128), 256, 0, stream>>>(
        attn, Wob, d_out, bo, M, DIM, DIM, DIM);
}

// Round 3
// 93.358 us; speedup vs baseline: 2.2549x; 1.2692x over previous
//
#include <hip/hip_runtime.h>
#include <hip/hip_bf16.h>

// CantorMultiheadFusion: x -> QKV proj -> sliding-window(K=64, clipped) MHA -> out proj (+bias)
// B=2 S=2048 DIM=1024 H=16 D=64 K=64
//
// Pipeline (5 launches):
//  1) cvt_all: f32->bf16 for x, [Wq;Wk;Wv], Wo (single kernel)
//  2) gemm_nt<0>: qkv[4096][3072] bf16 = x @ Wqkv^T   (2-phase double-buffered LDS)
//  3) transpose_v: Vt[b][h][64][2048] bf16
//  4) attn_fused: ALL rows via MFMA banded attention; edge clipping handled
//     exactly via log-multiplicity bias on clamped boundary keys
//  5) gemm_nt<1>: out[4096][1024] f32 = attn @ Wo^T + bo

typedef __attribute__((ext_vector_type(8))) short bf16x8;
typedef __attribute__((ext_vector_type(4))) float f32x4;

__device__ __forceinline__ unsigned short f32_to_bf16_rne(float f) {
    unsigned u = __float_as_uint(f);
    u += 0x7FFFu + ((u >> 16) & 1u);
    return (unsigned short)(u >> 16);
}
__device__ __forceinline__ float bf16_to_f32(unsigned short s) {
    return __uint_as_float(((unsigned)s) << 16);
}

// ---------------- merged conversion kernel ----------------
// covers x (1M float4), then Wq,Wk,Wv,Wo (256K float4 each)
__global__ __launch_bounds__(256) void cvt_all(
    const float4* __restrict__ x,
    const float4* __restrict__ Wq, const float4* __restrict__ Wk,
    const float4* __restrict__ Wv, const float4* __restrict__ Wo,
    ushort4* __restrict__ xb, ushort4* __restrict__ wqkv,
    ushort4* __restrict__ wob) {
    const int XN = (4096 * 1024) / 4;
    const int WN = (1024 * 1024) / 4;
    int i = blockIdx.x * 256 + threadIdx.x;
    float4 v;
    ushort4* dst;
    if (i < XN) {
        v = x[i];
        dst = xb + i;
    } else {
        int j = i - XN;
        int w = j >> 18;          // WN = 2^18
        int k = j & (WN - 1);
        const float4* s = (w == 0) ? Wq : (w == 1) ? Wk : (w == 2) ? Wv : Wo;
        v = s[k];
        dst = (w < 3) ? (wqkv + (size_t)w * WN + k) : (wob + k);
    }
    ushort4 o;
    o.x = f32_to_bf16_rne(v.x);
    o.y = f32_to_bf16_rne(v.y);
    o.z = f32_to_bf16_rne(v.z);
    o.w = f32_to_bf16_rne(v.w);
    *dst = o;
}

// ---------------- NT GEMM: C[M][N] = A[M][K] * B[N][K]^T ----------------
// 128x128 tile, BK=32, 4 waves (2x2), 2-phase double-buffered:
// stage(next) -> compute(cur) -> barrier (implicit vmcnt(0) drain).
template<int WRITE_MODE>
__global__ __launch_bounds__(256) void gemm_nt(
    const ushort* __restrict__ A, const ushort* __restrict__ B,
    void* __restrict__ Cout, const float* __restrict__ bias,
    int M, int N, int K, int ldc) {
    __shared__ ushort As[2][128 * 32];
    __shared__ ushort Bs[2][128 * 32];

    const int t    = threadIdx.x;
    const int lane = t & 63;
    const int wid  = t >> 6;
    const int wr   = wid >> 1;
    const int wc   = wid & 1;
    const int mBase = blockIdx.y * 128;
    const int nBase = blockIdx.x * 128;

    f32x4 acc[4][4] = {};

    const int ar = t >> 2;
    const int ac = (t & 3) * 8;
    const ushort* Aptr = A + (size_t)(mBase + ar) * K + ac;
    const ushort* Bptr = B + (size_t)(nBase + ar) * K + ac;

    const int kg = (lane >> 4) * 8;
    const int rA = wr * 64 + (lane & 15);
    const int rB = wc * 64 + (lane & 15);

    const int NT = K >> 5;

    auto stage = [&](int buf, int kt) {
        ushort* AsB = &As[buf][0] + t * 8;
        ushort* BsB = &Bs[buf][0] + t * 8;
        const int ko = kt * 32;
        __builtin_amdgcn_global_load_lds(
            (const __attribute__((address_space(1))) void*)(Aptr + ko),
            (__attribute__((address_space(3))) void*)AsB, 16, 0, 0);
        __builtin_amdgcn_global_load_lds(
            (const __attribute__((address_space(1))) void*)(Aptr + (size_t)64 * K + ko),
            (__attribute__((address_space(3))) void*)(AsB + 64 * 32), 16, 0, 0);
        __builtin_amdgcn_global_load_lds(
            (const __attribute__((address_space(1))) void*)(Bptr + ko),
            (__attribute__((address_space(3))) void*)BsB, 16, 0, 0);
        __builtin_amdgcn_global_load_lds(
            (const __attribute__((address_space(1))) void*)(Bptr + (size_t)64 * K + ko),
            (__attribute__((address_space(3))) void*)(BsB + 64 * 32), 16, 0, 0);
    };

    stage(0, 0);
    __syncthreads();

    for (int kt = 0; kt < NT; ++kt) {
        const int cur = kt & 1;
        if (kt + 1 < NT) stage(cur ^ 1, kt + 1);

        bf16x8 af[4], bfr[4];
#pragma unroll
        for (int m = 0; m < 4; ++m)
            af[m] = *reinterpret_cast<const bf16x8*>(&As[cur][(rA + m * 16) * 32 + kg]);
#pragma unroll
        for (int n = 0; n < 4; ++n)
            bfr[n] = *reinterpret_cast<const bf16x8*>(&Bs[cur][(rB + n * 16) * 32 + kg]);
#pragma unroll
        for (int m = 0; m < 4; ++m)
#pragma unroll
            for (int n = 0; n < 4; ++n)
                acc[m][n] = __builtin_amdgcn_mfma_f32_16x16x32_bf16(
                    af[m], bfr[n], acc[m][n], 0, 0, 0);

        __syncthreads();   // drains vmcnt(0): staged tile ready, reads of cur done
    }

    const int crow0 = mBase + wr * 64 + (lane >> 4) * 4;
    const int ccol0 = nBase + wc * 64 + (lane & 15);
#pragma unroll
    for (int m = 0; m < 4; ++m) {
#pragma unroll
        for (int n = 0; n < 4; ++n) {
            const int col = ccol0 + n * 16;
#pragma unroll
            for (int r = 0; r < 4; ++r) {
                const int row = crow0 + m * 16 + r;
                const float val = acc[m][n][r];
                if (WRITE_MODE == 0) {
                    ((ushort*)Cout)[(size_t)row * ldc + col] = f32_to_bf16_rne(val);
                } else {
                    ((float*)Cout)[(size_t)row * ldc + col] = val + bias[col];
                }
            }
        }
    }
}

// ---------------- V transpose: qkv V-part -> Vt[b][h][64][2048] ----------------
__global__ __launch_bounds__(256) void transpose_v(
    const ushort* __restrict__ qkv, ushort* __restrict__ Vt) {
    const int unit = blockIdx.x;       // 1024
    const int st = unit & 31;
    const int h  = (unit >> 5) & 15;
    const int b  = unit >> 9;
    __shared__ ushort tile[64][72];
    const int t = threadIdx.x;

    const int r0 = t >> 3;
    const int c0 = (t & 7) * 8;
#pragma unroll
    for (int i = 0; i < 2; ++i) {
        const int r = r0 + i * 32;
        bf16x8 v = *reinterpret_cast<const bf16x8*>(
            qkv + ((size_t)(b * 2048 + st * 64 + r)) * 3072 + 2048 + h * 64 + c0);
#pragma unroll
        for (int j = 0; j < 4; ++j) {
            ((uint*)&tile[r][c0])[j] = ((uint)(unsigned short)v[2 * j]) |
                                       (((uint)(unsigned short)v[2 * j + 1]) << 16);
        }
    }
    __syncthreads();

    const int d = t & 63, sg = t >> 6;
#pragma unroll
    for (int i = 0; i < 2; ++i) {
        const int s0 = sg * 16 + i * 8;
        ushort4 lo, hi;
        lo.x = tile[s0 + 0][d]; lo.y = tile[s0 + 1][d];
        lo.z = tile[s0 + 2][d]; lo.w = tile[s0 + 3][d];
        hi.x = tile[s0 + 4][d]; hi.y = tile[s0 + 5][d];
        hi.z = tile[s0 + 6][d]; hi.w = tile[s0 + 7][d];
        ushort* dst = Vt + (((size_t)(b * 16 + h) * 64 + d) * 2048) + st * 64 + s0;
        *reinterpret_cast<ushort4*>(dst) = lo;
        *reinterpret_cast<ushort4*>(dst + 4) = hi;
    }
}

// ---------------- unified banded MFMA attention (all rows) ----------------
// One wave per (b,h,32-row q-block). Virtual K window [qs-32, qs+63] (96 rows),
// addresses clamped to [0,2047]. Band mask qi<=vk<=qi+63 plus global bounds.
// Reference's clipped-window duplicate keys == softmax with additive
// log-multiplicity bias: +ln(33-s) on key 0 (s<=32), +ln(s-2015) on key 2047
// (s>=2016). Exact identity: c*exp(v) = exp(v + ln c).
#define PADW 104
__global__ __launch_bounds__(64) void attn_fused(
    const ushort* __restrict__ qkv, const ushort* __restrict__ Vt,
    ushort* __restrict__ attn_out) {
    const int lane = threadIdx.x;
    const int unit = blockIdx.x;       // 0..2047
    const int qb = unit & 63;
    const int h  = (unit >> 6) & 15;
    const int b  = unit >> 10;
    const int qs = qb * 32;
    const int kstart = qs - 32;
    const int c15 = lane & 15, g = lane >> 4;
    const bool edge = (qb == 0) || (qb == 63);

    __shared__ ushort P_lds[32 * PADW];

    // ---- QK^T (swapped): accS[kt][qt], row-dim = virtual k, col = qi ----
    const ushort* Qbase = qkv + (size_t)(b * 2048 + qs) * 3072 + h * 64;

    bf16x8 qf[2][2];
#pragma unroll
    for (int qt = 0; qt < 2; ++qt)
#pragma unroll
        for (int dc = 0; dc < 2; ++dc)
            qf[qt][dc] = *reinterpret_cast<const bf16x8*>(
                Qbase + (size_t)(qt * 16 + c15) * 3072 + dc * 32 + g * 8);

    f32x4 accS[6][2] = {};
#pragma unroll
    for (int kt = 0; kt < 6; ++kt) {
        int krow = kstart + kt * 16 + c15;
        krow = min(max(krow, 0), 2047);
        const ushort* Krow = qkv + (size_t)(b * 2048 + krow) * 3072 + 1024 + h * 64;
#pragma unroll
        for (int dc = 0; dc < 2; ++dc) {
            bf16x8 kf = *reinterpret_cast<const bf16x8*>(Krow + dc * 32 + g * 8);
#pragma unroll
            for (int qt = 0; qt < 2; ++qt)
                accS[kt][qt] = __builtin_amdgcn_mfma_f32_16x16x32_bf16(
                    kf, qf[qt][dc], accS[kt][qt], 0, 0, 0);
        }
    }

    // ---- pass 1: mask (+ bias on edge blocks), scale, row max ----
    float mx[2] = {-1e30f, -1e30f};
    if (edge) {
#pragma unroll
        for (int kt = 0; kt < 6; ++kt)
#pragma unroll
            for (int qt = 0; qt < 2; ++qt)
#pragma unroll
                for (int r = 0; r < 4; ++r) {
                    const int vk = kt * 16 + g * 4 + r;
                    const int qi = qt * 16 + c15;
                    const int ki = kstart + vk;
                    const int s_row = qs + qi;
                    float val = -1e30f;
                    if (vk >= qi && vk <= qi + 63 && ki >= 0 && ki <= 2047) {
                        float bias = 0.f;
                        if (ki == 0 && s_row <= 32)
                            bias = __logf((float)(33 - s_row));
                        if (ki == 2047 && s_row >= 2016)
                            bias = __logf((float)(s_row - 2015));
                        val = accS[kt][qt][r] * 0.125f + bias;
                    }
                    accS[kt][qt][r] = val;
                    mx[qt] = fmaxf(mx[qt], val);
                }
    } else {
#pragma unroll
        for (int kt = 0; kt < 6; ++kt)
#pragma unroll
            for (int qt = 0; qt < 2; ++qt)
#pragma unroll
                for (int r = 0; r < 4; ++r) {
                    const int vk = kt * 16 + g * 4 + r;
                    const int qi = qt * 16 + c15;
                    float val = -1e30f;
                    if (vk >= qi && vk <= qi + 63)
                        val = accS[kt][qt][r] * 0.125f;
                    accS[kt][qt][r] = val;
                    mx[qt] = fmaxf(mx[qt], val);
                }
    }
#pragma unroll
    for (int qt = 0; qt < 2; ++qt) {
        mx[qt] = fmaxf(mx[qt], __shfl_xor(mx[qt], 16));
        mx[qt] = fmaxf(mx[qt], __shfl_xor(mx[qt], 32));
    }

    // ---- pass 2: exp + row sum (masked entries underflow to 0) ----
    float sum[2] = {0.f, 0.f};
#pragma unroll
    for (int kt = 0; kt < 6; ++kt)
#pragma unroll
        for (int qt = 0; qt < 2; ++qt)
#pragma unroll
            for (int r = 0; r < 4; ++r) {
                float p = __expf(accS[kt][qt][r] - mx[qt]);
                accS[kt][qt][r] = p;
                sum[qt] += p;
            }
#pragma unroll
    for (int qt = 0; qt < 2; ++qt) {
        sum[qt] += __shfl_xor(sum[qt], 16);
        sum[qt] += __shfl_xor(sum[qt], 32);
        sum[qt] = 1.f / sum[qt];
    }

    // ---- pass 3: normalized P -> LDS (bf16) ----
#pragma unroll
    for (int kt = 0; kt < 6; ++kt)
#pragma unroll
        for (int qt = 0; qt < 2; ++qt)
#pragma unroll
            for (int r = 0; r < 4; ++r) {
                const int vk = kt * 16 + g * 4 + r;
                const int qi = qt * 16 + c15;
                P_lds[qi * PADW + vk] = f32_to_bf16_rne(accS[kt][qt][r] * sum[qt]);
            }

    // ---- PV: out[qi][d] = P(32x96) @ V(96x64), V rows from Vt (clamped) ----
    const ushort* VtH = Vt + ((size_t)(b * 16 + h) * 64) * 2048;
    f32x4 accO[2][4] = {};
#pragma unroll
    for (int u = 0; u < 3; ++u) {
        bf16x8 pf[2];
#pragma unroll
        for (int qt = 0; qt < 2; ++qt)
            pf[qt] = *reinterpret_cast<const bf16x8*>(
                &P_lds[(qt * 16 + c15) * PADW + u * 32 + g * 8]);
        int soff = kstart + u * 32 + g * 8;
        soff = min(max(soff, 0), 2040);   // chunks never straddle bounds (mult of 8)
#pragma unroll
        for (int dt = 0; dt < 4; ++dt) {
            bf16x8 vf = *reinterpret_cast<const bf16x8*>(
                VtH + (size_t)(dt * 16 + c15) * 2048 + soff);
#pragma unroll
            for (int qt = 0; qt < 2; ++qt)
                accO[qt][dt] = __builtin_amdgcn_mfma_f32_16x16x32_bf16(
                    pf[qt], vf, accO[qt][dt], 0, 0, 0);
        }
    }

    // ---- store ----
#pragma unroll
    for (int qt = 0; qt < 2; ++qt)
#pragma unroll
        for (int dt = 0; dt < 4; ++dt)
#pragma unroll
            for (int r = 0; r < 4; ++r) {
                const int row = b * 2048 + qs + qt * 16 + g * 4 + r;
                const int col = h * 64 + dt * 16 + c15;
                attn_out[(size_t)row * 1024 + col] = f32_to_bf16_rne(accO[qt][dt][r]);
            }
}

// ---------------- launch ----------------
extern "C" void kernel_launch(void* const* d_in, const int* in_sizes, int n_in,
                              void* d_out, int out_size, void* d_ws, size_t ws_size,
                              hipStream_t stream) {
    const float* x  = (const float*)d_in[0];
    const float* Wq = (const float*)d_in[2];
    const float* Wk = (const float*)d_in[3];
    const float* Wv = (const float*)d_in[4];
    const float* Wo = (const float*)d_in[5];
    const float* bo = (const float*)d_in[6];

    const int M = 4096;
    const int DIM = 1024;

    ushort* xb   = (ushort*)d_ws;                 // 4096*1024 (reused as Vt after gemm0)
    ushort* Wqkv = xb + (size_t)M * DIM;          // 3072*1024
    ushort* Wob  = Wqkv + (size_t)3072 * 1024;    // 1024*1024
    ushort* qkv  = Wob + (size_t)1024 * 1024;     // 4096*3072
    ushort* attn = qkv + (size_t)M * 3072;        // 4096*1024
    ushort* Vt   = xb;                            // alias: xb dead after gemm0

    cvt_all<<<8192, 256, 0, stream>>>(
        (const float4*)x, (const float4*)Wq, (const float4*)Wk,
        (const float4*)Wv, (const float4*)Wo,
        (ushort4*)xb, (ushort4*)Wqkv, (ushort4*)Wob);

    gemm_nt<0><<<dim3(3072 / 128, M / 128), 256, 0, stream>>>(
        xb, Wqkv, (void*)qkv, nullptr, M, 3072, DIM, 3072);

    transpose_v<<<1024, 256, 0, stream>>>(qkv, Vt);
    attn_fused<<<2048, 64, 0, stream>>>(qkv, Vt, attn);

    gemm_nt<1><<<dim3(DIM / 128, M / 128), 256, 0, stream>>>(
        attn, Wob, d_out, bo, M, DIM, DIM, DIM);
}

// Round 4
// 88.330 us; speedup vs baseline: 2.3832x; 1.0569x over previous
//
#include <hip/hip_runtime.h>
#include <hip/hip_bf16.h>

// CantorMultiheadFusion: x -> QKV proj -> sliding-window(K=64, clipped) MHA -> out proj (+bias)
// B=2 S=2048 DIM=1024 H=16 D=64 K=64
//
// Pipeline (5 launches):
//  1) cvt_all: f32->bf16 for x, [Wq;Wk;Wv], Wo
//  2) gemm256: qkv[4096][3072] bf16 = x @ Wqkv^T   (256x256 tile, BK=64, 8 waves,
//     counted-vmcnt 4-phase schedule, granule-XOR LDS swizzle)
//  3) transpose_v: Vt[b][h][64][2048] bf16
//  4) attn_fused: banded MFMA attention, edge clipping via log-multiplicity bias
//  5) gemm_nt<1>: out[4096][1024] f32 = attn @ Wo^T + bo  (128x128 2-phase; 256 blocks)

typedef __attribute__((ext_vector_type(8))) short bf16x8;
typedef __attribute__((ext_vector_type(4))) float f32x4;

__device__ __forceinline__ unsigned short f32_to_bf16_rne(float f) {
    unsigned u = __float_as_uint(f);
    u += 0x7FFFu + ((u >> 16) & 1u);
    return (unsigned short)(u >> 16);
}
__device__ __forceinline__ float bf16_to_f32(unsigned short s) {
    return __uint_as_float(((unsigned)s) << 16);
}

#define VMCNT4 asm volatile("s_waitcnt vmcnt(4)" ::: "memory")
#define VMCNT0 asm volatile("s_waitcnt vmcnt(0)" ::: "memory")
#define MEMFENCE asm volatile("" ::: "memory")

// ---------------- merged conversion kernel ----------------
__global__ __launch_bounds__(256) void cvt_all(
    const float4* __restrict__ x,
    const float4* __restrict__ Wq, const float4* __restrict__ Wk,
    const float4* __restrict__ Wv, const float4* __restrict__ Wo,
    ushort4* __restrict__ xb, ushort4* __restrict__ wqkv,
    ushort4* __restrict__ wob) {
    const int XN = (4096 * 1024) / 4;
    const int WN = (1024 * 1024) / 4;
    int i = blockIdx.x * 256 + threadIdx.x;
    float4 v;
    ushort4* dst;
    if (i < XN) {
        v = x[i];
        dst = xb + i;
    } else {
        int j = i - XN;
        int w = j >> 18;
        int k = j & (WN - 1);
        const float4* s = (w == 0) ? Wq : (w == 1) ? Wk : (w == 2) ? Wv : Wo;
        v = s[k];
        dst = (w < 3) ? (wqkv + (size_t)w * WN + k) : (wob + k);
    }
    ushort4 o;
    o.x = f32_to_bf16_rne(v.x);
    o.y = f32_to_bf16_rne(v.y);
    o.z = f32_to_bf16_rne(v.z);
    o.w = f32_to_bf16_rne(v.w);
    *dst = o;
}

// ---------------- 256x256 8-wave counted-vmcnt NT GEMM (bf16 out) ----------------
// C[M][N] = A[M][K] * B[N][K]^T. BM=BN=256, BK=64. 512 thr = 8 waves (2Mx4N),
// wave tile 128x64, acc[8][4] 16x16 frags. LDS 128KB:
//   smem[dbuf2][mat2(A,B)][khalf2][256rows x 32k] bf16, 16KB per (mat,khalf).
// Swizzle: within each 128B row-pair, 16B granule g -> g ^ (rowpair&7).
// Stage: global_load_lds width 16, LDS linear, source pre-swizzled (involution).
// Per K-tile: 4 phases x 16 MFMA; stage order [A-k0,B-k0,A-k1,B-k1];
// vmcnt(4)+barrier at ph0/ph2 only (loads stay in flight across barriers).
__global__ __launch_bounds__(512, 2) void gemm256(
    const ushort* __restrict__ A, const ushort* __restrict__ B,
    ushort* __restrict__ C, int M, int N, int K) {
    __shared__ ushort smem[65536];   // 128 KB

    const int t = threadIdx.x;
    const int l = t & 63, w = t >> 6;
    const int wm = w >> 2, wn = w & 3;     // 2 x 4 waves
    const int c15 = l & 15, g = l >> 4;
    const int mBase = blockIdx.y * 256, nBase = blockIdx.x * 256;
    const int NT = K >> 6;

    // staging source geometry: chunk j of this thread covers LDS bytes
    // L=(w*2+j)*1024 + l*16 of a 16KB (mat,khalf) region; inverse-swizzle -> (row, k8)
    int rr[2], kk8[2];
#pragma unroll
    for (int j = 0; j < 2; ++j) {
        const int L = (w * 2 + j) * 1024 + l * 16;
        const int rp = L >> 7;
        const int glog = ((L >> 4) & 7) ^ (rp & 7);
        rr[j] = rp * 2 + (glog >> 2);
        kk8[j] = (glog & 3) * 8;
    }

    // fragment read offsets (ushort units within a 16KB (mat,khalf) region)
    int aOff[8], bOff[4];
#pragma unroll
    for (int m8 = 0; m8 < 8; ++m8) {
        const int R = wm * 128 + m8 * 16 + c15;
        const int rp = R >> 1;
        aOff[m8] = rp * 64 + ((((R & 1) << 2) | g) ^ (rp & 7)) * 8;
    }
#pragma unroll
    for (int n4 = 0; n4 < 4; ++n4) {
        const int R = wn * 64 + n4 * 16 + c15;
        const int rp = R >> 1;
        bOff[n4] = rp * 64 + ((((R & 1) << 2) | g) ^ (rp & 7)) * 8;
    }

    f32x4 acc[8][4] = {};
    bf16x8 aF[8], bF0[2], bF1[2];

    auto stage = [&](int dbuf, int mat, int h, int kt, const ushort* Msrc, int rowBase) {
#pragma unroll
        for (int j = 0; j < 2; ++j) {
            const ushort* src = Msrc + (size_t)(rowBase + rr[j]) * K + kt * 64 + h * 32 + kk8[j];
            __builtin_amdgcn_global_load_lds(
                (const __attribute__((address_space(1))) void*)src,
                (__attribute__((address_space(3))) void*)
                    &smem[dbuf * 32768 + mat * 16384 + h * 8192 + (w * 2 + j) * 512 + l * 8],
                16, 0, 0);
        }
    };

#define LOAD_AF(CUR, KS)                                                        \
    {                                                                           \
        const int ab = (CUR) * 32768 + (KS) * 8192;                             \
        _Pragma("unroll") for (int m8 = 0; m8 < 8; ++m8)                        \
            aF[m8] = *reinterpret_cast<const bf16x8*>(&smem[ab + aOff[m8]]);    \
    }
#define LOAD_BF(DST, CUR, KS, NH)                                               \
    {                                                                           \
        const int bb = (CUR) * 32768 + 16384 + (KS) * 8192;                     \
        _Pragma("unroll") for (int n = 0; n < 2; ++n)                           \
            DST[n] = *reinterpret_cast<const bf16x8*>(&smem[bb + bOff[(NH) * 2 + n]]); \
    }
#define DO_MFMA(NH, BF)                                                         \
    __builtin_amdgcn_s_setprio(1);                                              \
    _Pragma("unroll") for (int m8 = 0; m8 < 8; ++m8) {                          \
        _Pragma("unroll") for (int n = 0; n < 2; ++n)                           \
            acc[m8][(NH) * 2 + n] = __builtin_amdgcn_mfma_f32_16x16x32_bf16(    \
                aF[m8], BF[n], acc[m8][(NH) * 2 + n], 0, 0, 0);                 \
    }                                                                           \
    __builtin_amdgcn_s_setprio(0);

    // prologue: stage tile 0 into buf 0, order [A-k0, B-k0, A-k1, B-k1]
    stage(0, 0, 0, 0, A, mBase);
    stage(0, 1, 0, 0, B, nBase);
    stage(0, 0, 1, 0, A, mBase);
    stage(0, 1, 1, 0, B, nBase);

    for (int kt = 0; kt < NT - 1; ++kt) {
        const int cur = kt & 1, nxt = cur ^ 1;
        // ph0: needs A-k0,B-k0 (oldest 4 loads)
        VMCNT4;
        __builtin_amdgcn_s_barrier();
        MEMFENCE;
        LOAD_AF(cur, 0);
        LOAD_BF(bF0, cur, 0, 0);
        stage(nxt, 0, 0, kt + 1, A, mBase);
        DO_MFMA(0, bF0);
        // ph1: B-k0 already landed
        LOAD_BF(bF1, cur, 0, 1);
        stage(nxt, 1, 0, kt + 1, B, nBase);
        DO_MFMA(1, bF1);
        // ph2: needs A-k1,B-k1
        VMCNT4;
        __builtin_amdgcn_s_barrier();
        MEMFENCE;
        LOAD_AF(cur, 1);
        LOAD_BF(bF0, cur, 1, 0);
        stage(nxt, 0, 1, kt + 1, A, mBase);
        DO_MFMA(0, bF0);
        // ph3
        LOAD_BF(bF1, cur, 1, 1);
        stage(nxt, 1, 1, kt + 1, B, nBase);
        DO_MFMA(1, bF1);
    }

    // epilogue tile NT-1 (no staging)
    {
        const int cur = (NT - 1) & 1;
        VMCNT4;
        __builtin_amdgcn_s_barrier();
        MEMFENCE;
        LOAD_AF(cur, 0);
        LOAD_BF(bF0, cur, 0, 0);
        DO_MFMA(0, bF0);
        LOAD_BF(bF1, cur, 0, 1);
        DO_MFMA(1, bF1);
        VMCNT0;
        __builtin_amdgcn_s_barrier();
        MEMFENCE;
        LOAD_AF(cur, 1);
        LOAD_BF(bF0, cur, 1, 0);
        DO_MFMA(0, bF0);
        LOAD_BF(bF1, cur, 1, 1);
        DO_MFMA(1, bF1);
    }

    // epilogue: D row=(lane>>4)*4+reg, col=lane&15
#pragma unroll
    for (int m8 = 0; m8 < 8; ++m8) {
#pragma unroll
        for (int n4 = 0; n4 < 4; ++n4) {
            const int col = nBase + wn * 64 + n4 * 16 + c15;
#pragma unroll
            for (int r = 0; r < 4; ++r) {
                const int row = mBase + wm * 128 + m8 * 16 + g * 4 + r;
                C[(size_t)row * N + col] = f32_to_bf16_rne(acc[m8][n4][r]);
            }
        }
    }
#undef LOAD_AF
#undef LOAD_BF
#undef DO_MFMA
}

// ---------------- 128x128 2-phase NT GEMM (f32 + bias out, for out-proj) ----------------
template<int WRITE_MODE>
__global__ __launch_bounds__(256) void gemm_nt(
    const ushort* __restrict__ A, const ushort* __restrict__ B,
    void* __restrict__ Cout, const float* __restrict__ bias,
    int M, int N, int K, int ldc) {
    __shared__ ushort As[2][128 * 32];
    __shared__ ushort Bs[2][128 * 32];

    const int t    = threadIdx.x;
    const int lane = t & 63;
    const int wid  = t >> 6;
    const int wr   = wid >> 1;
    const int wc   = wid & 1;
    const int mBase = blockIdx.y * 128;
    const int nBase = blockIdx.x * 128;

    f32x4 acc[4][4] = {};

    const int ar = t >> 2;
    const int ac = (t & 3) * 8;
    const ushort* Aptr = A + (size_t)(mBase + ar) * K + ac;
    const ushort* Bptr = B + (size_t)(nBase + ar) * K + ac;

    const int kg = (lane >> 4) * 8;
    const int rA = wr * 64 + (lane & 15);
    const int rB = wc * 64 + (lane & 15);

    const int NT = K >> 5;

    auto stage = [&](int buf, int kt) {
        ushort* AsB = &As[buf][0] + t * 8;
        ushort* BsB = &Bs[buf][0] + t * 8;
        const int ko = kt * 32;
        __builtin_amdgcn_global_load_lds(
            (const __attribute__((address_space(1))) void*)(Aptr + ko),
            (__attribute__((address_space(3))) void*)AsB, 16, 0, 0);
        __builtin_amdgcn_global_load_lds(
            (const __attribute__((address_space(1))) void*)(Aptr + (size_t)64 * K + ko),
            (__attribute__((address_space(3))) void*)(AsB + 64 * 32), 16, 0, 0);
        __builtin_amdgcn_global_load_lds(
            (const __attribute__((address_space(1))) void*)(Bptr + ko),
            (__attribute__((address_space(3))) void*)BsB, 16, 0, 0);
        __builtin_amdgcn_global_load_lds(
            (const __attribute__((address_space(1))) void*)(Bptr + (size_t)64 * K + ko),
            (__attribute__((address_space(3))) void*)(BsB + 64 * 32), 16, 0, 0);
    };

    stage(0, 0);
    __syncthreads();

    for (int kt = 0; kt < NT; ++kt) {
        const int cur = kt & 1;
        if (kt + 1 < NT) stage(cur ^ 1, kt + 1);

        bf16x8 af[4], bfr[4];
#pragma unroll
        for (int m = 0; m < 4; ++m)
            af[m] = *reinterpret_cast<const bf16x8*>(&As[cur][(rA + m * 16) * 32 + kg]);
#pragma unroll
        for (int n = 0; n < 4; ++n)
            bfr[n] = *reinterpret_cast<const bf16x8*>(&Bs[cur][(rB + n * 16) * 32 + kg]);
#pragma unroll
        for (int m = 0; m < 4; ++m)
#pragma unroll
            for (int n = 0; n < 4; ++n)
                acc[m][n] = __builtin_amdgcn_mfma_f32_16x16x32_bf16(
                    af[m], bfr[n], acc[m][n], 0, 0, 0);

        __syncthreads();
    }

    const int crow0 = mBase + wr * 64 + (lane >> 4) * 4;
    const int ccol0 = nBase + wc * 64 + (lane & 15);
#pragma unroll
    for (int m = 0; m < 4; ++m) {
#pragma unroll
        for (int n = 0; n < 4; ++n) {
            const int col = ccol0 + n * 16;
#pragma unroll
            for (int r = 0; r < 4; ++r) {
                const int row = crow0 + m * 16 + r;
                const float val = acc[m][n][r];
                if (WRITE_MODE == 0) {
                    ((ushort*)Cout)[(size_t)row * ldc + col] = f32_to_bf16_rne(val);
                } else {
                    ((float*)Cout)[(size_t)row * ldc + col] = val + bias[col];
                }
            }
        }
    }
}

// ---------------- V transpose: qkv V-part -> Vt[b][h][64][2048] ----------------
__global__ __launch_bounds__(256) void transpose_v(
    const ushort* __restrict__ qkv, ushort* __restrict__ Vt) {
    const int unit = blockIdx.x;
    const int st = unit & 31;
    const int h  = (unit >> 5) & 15;
    const int b  = unit >> 9;
    __shared__ ushort tile[64][72];
    const int t = threadIdx.x;

    const int r0 = t >> 3;
    const int c0 = (t & 7) * 8;
#pragma unroll
    for (int i = 0; i < 2; ++i) {
        const int r = r0 + i * 32;
        bf16x8 v = *reinterpret_cast<const bf16x8*>(
            qkv + ((size_t)(b * 2048 + st * 64 + r)) * 3072 + 2048 + h * 64 + c0);
#pragma unroll
        for (int j = 0; j < 4; ++j) {
            ((uint*)&tile[r][c0])[j] = ((uint)(unsigned short)v[2 * j]) |
                                       (((uint)(unsigned short)v[2 * j + 1]) << 16);
        }
    }
    __syncthreads();

    const int d = t & 63, sg = t >> 6;
#pragma unroll
    for (int i = 0; i < 2; ++i) {
        const int s0 = sg * 16 + i * 8;
        ushort4 lo, hi;
        lo.x = tile[s0 + 0][d]; lo.y = tile[s0 + 1][d];
        lo.z = tile[s0 + 2][d]; lo.w = tile[s0 + 3][d];
        hi.x = tile[s0 + 4][d]; hi.y = tile[s0 + 5][d];
        hi.z = tile[s0 + 6][d]; hi.w = tile[s0 + 7][d];
        ushort* dst = Vt + (((size_t)(b * 16 + h) * 64 + d) * 2048) + st * 64 + s0;
        *reinterpret_cast<ushort4*>(dst) = lo;
        *reinterpret_cast<ushort4*>(dst + 4) = hi;
    }
}

// ---------------- unified banded MFMA attention ----------------
#define PADW 104
__global__ __launch_bounds__(64) void attn_fused(
    const ushort* __restrict__ qkv, const ushort* __restrict__ Vt,
    ushort* __restrict__ attn_out) {
    const int lane = threadIdx.x;
    const int unit = blockIdx.x;
    const int qb = unit & 63;
    const int h  = (unit >> 6) & 15;
    const int b  = unit >> 10;
    const int qs = qb * 32;
    const int kstart = qs - 32;
    const int c15 = lane & 15, g = lane >> 4;
    const bool edge = (qb == 0) || (qb == 63);

    __shared__ ushort P_lds[32 * PADW];

    const ushort* Qbase = qkv + (size_t)(b * 2048 + qs) * 3072 + h * 64;

    bf16x8 qf[2][2];
#pragma unroll
    for (int qt = 0; qt < 2; ++qt)
#pragma unroll
        for (int dc = 0; dc < 2; ++dc)
            qf[qt][dc] = *reinterpret_cast<const bf16x8*>(
                Qbase + (size_t)(qt * 16 + c15) * 3072 + dc * 32 + g * 8);

    f32x4 accS[6][2] = {};
#pragma unroll
    for (int kt = 0; kt < 6; ++kt) {
        int krow = kstart + kt * 16 + c15;
        krow = min(max(krow, 0), 2047);
        const ushort* Krow = qkv + (size_t)(b * 2048 + krow) * 3072 + 1024 + h * 64;
#pragma unroll
        for (int dc = 0; dc < 2; ++dc) {
            bf16x8 kf = *reinterpret_cast<const bf16x8*>(Krow + dc * 32 + g * 8);
#pragma unroll
            for (int qt = 0; qt < 2; ++qt)
                accS[kt][qt] = __builtin_amdgcn_mfma_f32_16x16x32_bf16(
                    kf, qf[qt][dc], accS[kt][qt], 0, 0, 0);
        }
    }

    float mx[2] = {-1e30f, -1e30f};
    if (edge) {
#pragma unroll
        for (int kt = 0; kt < 6; ++kt)
#pragma unroll
            for (int qt = 0; qt < 2; ++qt)
#pragma unroll
                for (int r = 0; r < 4; ++r) {
                    const int vk = kt * 16 + g * 4 + r;
                    const int qi = qt * 16 + c15;
                    const int ki = kstart + vk;
                    const int s_row = qs + qi;
                    float val = -1e30f;
                    if (vk >= qi && vk <= qi + 63 && ki >= 0 && ki <= 2047) {
                        float bias = 0.f;
                        if (ki == 0 && s_row <= 32)
                            bias = __logf((float)(33 - s_row));
                        if (ki == 2047 && s_row >= 2016)
                            bias = __logf((float)(s_row - 2015));
                        val = accS[kt][qt][r] * 0.125f + bias;
                    }
                    accS[kt][qt][r] = val;
                    mx[qt] = fmaxf(mx[qt], val);
                }
    } else {
#pragma unroll
        for (int kt = 0; kt < 6; ++kt)
#pragma unroll
            for (int qt = 0; qt < 2; ++qt)
#pragma unroll
                for (int r = 0; r < 4; ++r) {
                    const int vk = kt * 16 + g * 4 + r;
                    const int qi = qt * 16 + c15;
                    float val = -1e30f;
                    if (vk >= qi && vk <= qi + 63)
                        val = accS[kt][qt][r] * 0.125f;
                    accS[kt][qt][r] = val;
                    mx[qt] = fmaxf(mx[qt], val);
                }
    }
#pragma unroll
    for (int qt = 0; qt < 2; ++qt) {
        mx[qt] = fmaxf(mx[qt], __shfl_xor(mx[qt], 16));
        mx[qt] = fmaxf(mx[qt], __shfl_xor(mx[qt], 32));
    }

    float sum[2] = {0.f, 0.f};
#pragma unroll
    for (int kt = 0; kt < 6; ++kt)
#pragma unroll
        for (int qt = 0; qt < 2; ++qt)
#pragma unroll
            for (int r = 0; r < 4; ++r) {
                float p = __expf(accS[kt][qt][r] - mx[qt]);
                accS[kt][qt][r] = p;
                sum[qt] += p;
            }
#pragma unroll
    for (int qt = 0; qt < 2; ++qt) {
        sum[qt] += __shfl_xor(sum[qt], 16);
        sum[qt] += __shfl_xor(sum[qt], 32);
        sum[qt] = 1.f / sum[qt];
    }

#pragma unroll
    for (int kt = 0; kt < 6; ++kt)
#pragma unroll
        for (int qt = 0; qt < 2; ++qt)
#pragma unroll
            for (int r = 0; r < 4; ++r) {
                const int vk = kt * 16 + g * 4 + r;
                const int qi = qt * 16 + c15;
                P_lds[qi * PADW + vk] = f32_to_bf16_rne(accS[kt][qt][r] * sum[qt]);
            }

    const ushort* VtH = Vt + ((size_t)(b * 16 + h) * 64) * 2048;
    f32x4 accO[2][4] = {};
#pragma unroll
    for (int u = 0; u < 3; ++u) {
        bf16x8 pf[2];
#pragma unroll
        for (int qt = 0; qt < 2; ++qt)
            pf[qt] = *reinterpret_cast<const bf16x8*>(
                &P_lds[(qt * 16 + c15) * PADW + u * 32 + g * 8]);
        int soff = kstart + u * 32 + g * 8;
        soff = min(max(soff, 0), 2040);
#pragma unroll
        for (int dt = 0; dt < 4; ++dt) {
            bf16x8 vf = *reinterpret_cast<const bf16x8*>(
                VtH + (size_t)(dt * 16 + c15) * 2048 + soff);
#pragma unroll
            for (int qt = 0; qt < 2; ++qt)
                accO[qt][dt] = __builtin_amdgcn_mfma_f32_16x16x32_bf16(
                    pf[qt], vf, accO[qt][dt], 0, 0, 0);
        }
    }

#pragma unroll
    for (int qt = 0; qt < 2; ++qt)
#pragma unroll
        for (int dt = 0; dt < 4; ++dt)
#pragma unroll
            for (int r = 0; r < 4; ++r) {
                const int row = b * 2048 + qs + qt * 16 + g * 4 + r;
                const int col = h * 64 + dt * 16 + c15;
                attn_out[(size_t)row * 1024 + col] = f32_to_bf16_rne(accO[qt][dt][r]);
            }
}

// ---------------- launch ----------------
extern "C" void kernel_launch(void* const* d_in, const int* in_sizes, int n_in,
                              void* d_out, int out_size, void* d_ws, size_t ws_size,
                              hipStream_t stream) {
    const float* x  = (const float*)d_in[0];
    const float* Wq = (const float*)d_in[2];
    const float* Wk = (const float*)d_in[3];
    const float* Wv = (const float*)d_in[4];
    const float* Wo = (const float*)d_in[5];
    const float* bo = (const float*)d_in[6];

    const int M = 4096;
    const int DIM = 1024;

    ushort* xb   = (ushort*)d_ws;                 // 4096*1024 (reused as Vt after gemm0)
    ushort* Wqkv = xb + (size_t)M * DIM;          // 3072*1024
    ushort* Wob  = Wqkv + (size_t)3072 * 1024;    // 1024*1024
    ushort* qkv  = Wob + (size_t)1024 * 1024;     // 4096*3072
    ushort* attn = qkv + (size_t)M * 3072;        // 4096*1024
    ushort* Vt   = xb;

    cvt_all<<<8192, 256, 0, stream>>>(
        (const float4*)x, (const float4*)Wq, (const float4*)Wk,
        (const float4*)Wv, (const float4*)Wo,
        (ushort4*)xb, (ushort4*)Wqkv, (ushort4*)Wob);

    gemm256<<<dim3(3072 / 256, M / 256), 512, 0, stream>>>(
        xb, Wqkv, qkv, M, 3072, DIM);

    transpose_v<<<1024, 256, 0, stream>>>(qkv, Vt);
    attn_fused<<<2048, 64, 0, stream>>>(qkv, Vt, attn);

    gemm_nt<1><<<dim3(DIM / 128, M / 128), 256, 0, stream>>>(
        attn, Wob, d_out, bo, M, DIM, DIM, DIM);
}

// Round 6
// 77.904 us; speedup vs baseline: 2.7022x; 1.1338x over previous
//
#include <hip/hip_runtime.h>
#include <hip/hip_bf16.h>

// CantorMultiheadFusion: x -> QKV proj -> sliding-window(K=64, clipped) MHA -> out proj (+bias)
// B=2 S=2048 DIM=1024 H=16 D=64 K=64
//
// Pipeline (4 launches):
//  1) cvt_all: f32->bf16 for x, [Wq;Wk;Wv], Wo
//  2) gemm256: qkv[4096][3072] bf16 = x @ Wqkv^T (256x256, BK=64, 8 waves, counted-vmcnt
//     4-phase, granule-XOR swizzle). V-range blocks write TRANSPOSED into Vt instead of qkv.
//  3) attn_fused: banded MFMA attention (4 waves/block), edge clipping via log-multiplicity bias
//  4) gemm128p: out[4096][1024] f32 = attn @ Wo^T + bo (same 4-phase schedule at 128^2, 2 blk/CU)

typedef __attribute__((ext_vector_type(8))) short bf16x8;
typedef __attribute__((ext_vector_type(4))) float f32x4;

__device__ __forceinline__ unsigned short f32_to_bf16_rne(float f) {
    unsigned u = __float_as_uint(f);
    u += 0x7FFFu + ((u >> 16) & 1u);
    return (unsigned short)(u >> 16);
}
__device__ __forceinline__ float bf16_to_f32(unsigned short s) {
    return __uint_as_float(((unsigned)s) << 16);
}

#define VMCNT4 asm volatile("s_waitcnt vmcnt(4)" ::: "memory")
#define VMCNT0 asm volatile("s_waitcnt vmcnt(0)" ::: "memory")
#define MEMFENCE asm volatile("" ::: "memory")

// ---------------- merged conversion kernel ----------------
__global__ __launch_bounds__(256) void cvt_all(
    const float4* __restrict__ x,
    const float4* __restrict__ Wq, const float4* __restrict__ Wk,
    const float4* __restrict__ Wv, const float4* __restrict__ Wo,
    ushort4* __restrict__ xb, ushort4* __restrict__ wqkv,
    ushort4* __restrict__ wob) {
    const int XN = (4096 * 1024) / 4;
    const int WN = (1024 * 1024) / 4;
    int i = blockIdx.x * 256 + threadIdx.x;
    float4 v;
    ushort4* dst;
    if (i < XN) {
        v = x[i];
        dst = xb + i;
    } else {
        int j = i - XN;
        int w = j >> 18;
        int k = j & (WN - 1);
        const float4* s = (w == 0) ? Wq : (w == 1) ? Wk : (w == 2) ? Wv : Wo;
        v = s[k];
        dst = (w < 3) ? (wqkv + (size_t)w * WN + k) : (wob + k);
    }
    ushort4 o;
    o.x = f32_to_bf16_rne(v.x);
    o.y = f32_to_bf16_rne(v.y);
    o.z = f32_to_bf16_rne(v.z);
    o.w = f32_to_bf16_rne(v.w);
    *dst = o;
}

// ---------------- 256x256 8-wave counted-vmcnt NT GEMM ----------------
// C[M][N] = A[M][K]*B[N][K]^T. Q/K columns -> qkv (bf16). V columns (col>=2048)
// -> transposed store into Vt[b][h][64][2048] (qkv V-range left unwritten).
__global__ __launch_bounds__(512, 2) void gemm256(
    const ushort* __restrict__ A, const ushort* __restrict__ B,
    ushort* __restrict__ C, ushort* __restrict__ Vt, int M, int N, int K) {
    __shared__ ushort smem[65536];   // 128 KB

    const int t = threadIdx.x;
    const int l = t & 63, w = t >> 6;
    const int wm = w >> 2, wn = w & 3;     // 2 x 4 waves
    const int c15 = l & 15, g = l >> 4;
    const int mBase = blockIdx.y * 256, nBase = blockIdx.x * 256;
    const int NT = K >> 6;

    int rr[2], kk8[2];
#pragma unroll
    for (int j = 0; j < 2; ++j) {
        const int L = (w * 2 + j) * 1024 + l * 16;
        const int rp = L >> 7;
        const int glog = ((L >> 4) & 7) ^ (rp & 7);
        rr[j] = rp * 2 + (glog >> 2);
        kk8[j] = (glog & 3) * 8;
    }

    int aOff[8], bOff[4];
#pragma unroll
    for (int m8 = 0; m8 < 8; ++m8) {
        const int R = wm * 128 + m8 * 16 + c15;
        const int rp = R >> 1;
        aOff[m8] = rp * 64 + ((((R & 1) << 2) | g) ^ (rp & 7)) * 8;
    }
#pragma unroll
    for (int n4 = 0; n4 < 4; ++n4) {
        const int R = wn * 64 + n4 * 16 + c15;
        const int rp = R >> 1;
        bOff[n4] = rp * 64 + ((((R & 1) << 2) | g) ^ (rp & 7)) * 8;
    }

    f32x4 acc[8][4] = {};
    bf16x8 aF[8], bF0[2], bF1[2];

    auto stage = [&](int dbuf, int mat, int h, int kt, const ushort* Msrc, int rowBase) {
#pragma unroll
        for (int j = 0; j < 2; ++j) {
            const ushort* src = Msrc + (size_t)(rowBase + rr[j]) * K + kt * 64 + h * 32 + kk8[j];
            __builtin_amdgcn_global_load_lds(
                (const __attribute__((address_space(1))) void*)src,
                (__attribute__((address_space(3))) void*)
                    &smem[dbuf * 32768 + mat * 16384 + h * 8192 + (w * 2 + j) * 512 + l * 8],
                16, 0, 0);
        }
    };

#define LOAD_AF(CUR, KS)                                                        \
    {                                                                           \
        const int ab = (CUR) * 32768 + (KS) * 8192;                             \
        _Pragma("unroll") for (int m8 = 0; m8 < 8; ++m8)                        \
            aF[m8] = *reinterpret_cast<const bf16x8*>(&smem[ab + aOff[m8]]);    \
    }
#define LOAD_BF(DST, CUR, KS, NH)                                               \
    {                                                                           \
        const int bb = (CUR) * 32768 + 16384 + (KS) * 8192;                     \
        _Pragma("unroll") for (int n = 0; n < 2; ++n)                           \
            DST[n] = *reinterpret_cast<const bf16x8*>(&smem[bb + bOff[(NH) * 2 + n]]); \
    }
#define DO_MFMA(NH, BF)                                                         \
    __builtin_amdgcn_s_setprio(1);                                              \
    _Pragma("unroll") for (int m8 = 0; m8 < 8; ++m8) {                          \
        _Pragma("unroll") for (int n = 0; n < 2; ++n)                           \
            acc[m8][(NH) * 2 + n] = __builtin_amdgcn_mfma_f32_16x16x32_bf16(    \
                aF[m8], BF[n], acc[m8][(NH) * 2 + n], 0, 0, 0);                 \
    }                                                                           \
    __builtin_amdgcn_s_setprio(0);

    stage(0, 0, 0, 0, A, mBase);
    stage(0, 1, 0, 0, B, nBase);
    stage(0, 0, 1, 0, A, mBase);
    stage(0, 1, 1, 0, B, nBase);

    for (int kt = 0; kt < NT - 1; ++kt) {
        const int cur = kt & 1, nxt = cur ^ 1;
        VMCNT4;
        __builtin_amdgcn_s_barrier();
        MEMFENCE;
        LOAD_AF(cur, 0);
        LOAD_BF(bF0, cur, 0, 0);
        stage(nxt, 0, 0, kt + 1, A, mBase);
        DO_MFMA(0, bF0);
        LOAD_BF(bF1, cur, 0, 1);
        stage(nxt, 1, 0, kt + 1, B, nBase);
        DO_MFMA(1, bF1);
        VMCNT4;
        __builtin_amdgcn_s_barrier();
        MEMFENCE;
        LOAD_AF(cur, 1);
        LOAD_BF(bF0, cur, 1, 0);
        stage(nxt, 0, 1, kt + 1, A, mBase);
        DO_MFMA(0, bF0);
        LOAD_BF(bF1, cur, 1, 1);
        stage(nxt, 1, 1, kt + 1, B, nBase);
        DO_MFMA(1, bF1);
    }

    {
        const int cur = (NT - 1) & 1;
        VMCNT4;
        __builtin_amdgcn_s_barrier();
        MEMFENCE;
        LOAD_AF(cur, 0);
        LOAD_BF(bF0, cur, 0, 0);
        DO_MFMA(0, bF0);
        LOAD_BF(bF1, cur, 0, 1);
        DO_MFMA(1, bF1);
        VMCNT0;
        __builtin_amdgcn_s_barrier();
        MEMFENCE;
        LOAD_AF(cur, 1);
        LOAD_BF(bF0, cur, 1, 0);
        DO_MFMA(0, bF0);
        LOAD_BF(bF1, cur, 1, 1);
        DO_MFMA(1, bF1);
    }

    if (nBase < 2048) {
        // Q/K columns: normal row-major bf16 store into qkv
#pragma unroll
        for (int m8 = 0; m8 < 8; ++m8) {
#pragma unroll
            for (int n4 = 0; n4 < 4; ++n4) {
                const int col = nBase + wn * 64 + n4 * 16 + c15;
#pragma unroll
                for (int r = 0; r < 4; ++r) {
                    const int row = mBase + wm * 128 + m8 * 16 + g * 4 + r;
                    C[(size_t)row * N + col] = f32_to_bf16_rne(acc[m8][n4][r]);
                }
            }
        }
    } else {
        // V columns: transposed store into Vt[b][h][d][s]; 4 consecutive s per thread = 8B
        const int bb_ = mBase >> 11;
#pragma unroll
        for (int m8 = 0; m8 < 8; ++m8) {
            const int s0 = (mBase & 2047) + wm * 128 + m8 * 16 + g * 4;
#pragma unroll
            for (int n4 = 0; n4 < 4; ++n4) {
                const int vcol = nBase - 2048 + wn * 64 + n4 * 16 + c15;
                const int hh = vcol >> 6, dd = vcol & 63;
                ushort4 vv;
                vv.x = f32_to_bf16_rne(acc[m8][n4][0]);
                vv.y = f32_to_bf16_rne(acc[m8][n4][1]);
                vv.z = f32_to_bf16_rne(acc[m8][n4][2]);
                vv.w = f32_to_bf16_rne(acc[m8][n4][3]);
                *reinterpret_cast<ushort4*>(
                    &Vt[(((size_t)(bb_ * 16 + hh) * 64 + dd) << 11) + s0]) = vv;
            }
        }
    }
#undef LOAD_AF
#undef LOAD_BF
#undef DO_MFMA
}

// ---------------- 128x128 4-wave counted-vmcnt NT GEMM (f32 + bias out) ----------------
// Same schedule/swizzle as gemm256 at quarter size; 64KB LDS -> 2 blocks/CU.
__global__ __launch_bounds__(256, 2) void gemm128p(
    const ushort* __restrict__ A, const ushort* __restrict__ B,
    float* __restrict__ C, const float* __restrict__ bias, int M, int N, int K) {
    __shared__ ushort smem[32768];   // 64 KB: [dbuf2][mat2][khalf2][128x32]

    const int t = threadIdx.x;
    const int l = t & 63, w = t >> 6;      // 4 waves
    const int wm = w >> 1, wn = w & 1;     // 2 x 2
    const int c15 = l & 15, g = l >> 4;
    const int mBase = blockIdx.y * 128, nBase = blockIdx.x * 128;
    const int NT = K >> 6;

    int rr[2], kk8[2];
#pragma unroll
    for (int j = 0; j < 2; ++j) {
        const int L = (w * 2 + j) * 1024 + l * 16;   // 0..8191 within 8KB region
        const int rp = L >> 7;
        const int glog = ((L >> 4) & 7) ^ (rp & 7);
        rr[j] = rp * 2 + (glog >> 2);
        kk8[j] = (glog & 3) * 8;
    }

    int aOff[4], bOff[4];
#pragma unroll
    for (int m8 = 0; m8 < 4; ++m8) {
        const int R = wm * 64 + m8 * 16 + c15;
        const int rp = R >> 1;
        aOff[m8] = rp * 64 + ((((R & 1) << 2) | g) ^ (rp & 7)) * 8;
    }
#pragma unroll
    for (int n4 = 0; n4 < 4; ++n4) {
        const int R = wn * 64 + n4 * 16 + c15;
        const int rp = R >> 1;
        bOff[n4] = rp * 64 + ((((R & 1) << 2) | g) ^ (rp & 7)) * 8;
    }

    f32x4 acc[4][4] = {};
    bf16x8 aF[4], bF0[2], bF1[2];

    auto stage = [&](int dbuf, int mat, int h, int kt, const ushort* Msrc, int rowBase) {
#pragma unroll
        for (int j = 0; j < 2; ++j) {
            const ushort* src = Msrc + (size_t)(rowBase + rr[j]) * K + kt * 64 + h * 32 + kk8[j];
            __builtin_amdgcn_global_load_lds(
                (const __attribute__((address_space(1))) void*)src,
                (__attribute__((address_space(3))) void*)
                    &smem[dbuf * 16384 + mat * 8192 + h * 4096 + (w * 2 + j) * 512 + l * 8],
                16, 0, 0);
        }
    };

#define LOAD_AF(CUR, KS)                                                        \
    {                                                                           \
        const int ab = (CUR) * 16384 + (KS) * 4096;                             \
        _Pragma("unroll") for (int m8 = 0; m8 < 4; ++m8)                        \
            aF[m8] = *reinterpret_cast<const bf16x8*>(&smem[ab + aOff[m8]]);    \
    }
#define LOAD_BF(DST, CUR, KS, NH)                                               \
    {                                                                           \
        const int bb = (CUR) * 16384 + 8192 + (KS) * 4096;                      \
        _Pragma("unroll") for (int n = 0; n < 2; ++n)                           \
            DST[n] = *reinterpret_cast<const bf16x8*>(&smem[bb + bOff[(NH) * 2 + n]]); \
    }
#define DO_MFMA(NH, BF)                                                         \
    __builtin_amdgcn_s_setprio(1);                                              \
    _Pragma("unroll") for (int m8 = 0; m8 < 4; ++m8) {                          \
        _Pragma("unroll") for (int n = 0; n < 2; ++n)                           \
            acc[m8][(NH) * 2 + n] = __builtin_amdgcn_mfma_f32_16x16x32_bf16(    \
                aF[m8], BF[n], acc[m8][(NH) * 2 + n], 0, 0, 0);                 \
    }                                                                           \
    __builtin_amdgcn_s_setprio(0);

    stage(0, 0, 0, 0, A, mBase);
    stage(0, 1, 0, 0, B, nBase);
    stage(0, 0, 1, 0, A, mBase);
    stage(0, 1, 1, 0, B, nBase);

    for (int kt = 0; kt < NT - 1; ++kt) {
        const int cur = kt & 1, nxt = cur ^ 1;
        VMCNT4;
        __builtin_amdgcn_s_barrier();
        MEMFENCE;
        LOAD_AF(cur, 0);
        LOAD_BF(bF0, cur, 0, 0);
        stage(nxt, 0, 0, kt + 1, A, mBase);
        DO_MFMA(0, bF0);
        LOAD_BF(bF1, cur, 0, 1);
        stage(nxt, 1, 0, kt + 1, B, nBase);
        DO_MFMA(1, bF1);
        VMCNT4;
        __builtin_amdgcn_s_barrier();
        MEMFENCE;
        LOAD_AF(cur, 1);
        LOAD_BF(bF0, cur, 1, 0);
        stage(nxt, 0, 1, kt + 1, A, mBase);
        DO_MFMA(0, bF0);
        LOAD_BF(bF1, cur, 1, 1);
        stage(nxt, 1, 1, kt + 1, B, nBase);
        DO_MFMA(1, bF1);
    }

    {
        const int cur = (NT - 1) & 1;
        VMCNT4;
        __builtin_amdgcn_s_barrier();
        MEMFENCE;
        LOAD_AF(cur, 0);
        LOAD_BF(bF0, cur, 0, 0);
        DO_MFMA(0, bF0);
        LOAD_BF(bF1, cur, 0, 1);
        DO_MFMA(1, bF1);
        VMCNT0;
        __builtin_amdgcn_s_barrier();
        MEMFENCE;
        LOAD_AF(cur, 1);
        LOAD_BF(bF0, cur, 1, 0);
        DO_MFMA(0, bF0);
        LOAD_BF(bF1, cur, 1, 1);
        DO_MFMA(1, bF1);
    }

#pragma unroll
    for (int m8 = 0; m8 < 4; ++m8) {
#pragma unroll
        for (int n4 = 0; n4 < 4; ++n4) {
            const int col = nBase + wn * 64 + n4 * 16 + c15;
#pragma unroll
            for (int r = 0; r < 4; ++r) {
                const int row = mBase + wm * 64 + m8 * 16 + g * 4 + r;
                C[(size_t)row * N + col] = acc[m8][n4][r] + bias[col];
            }
        }
    }
#undef LOAD_AF
#undef LOAD_BF
#undef DO_MFMA
}

// ---------------- unified banded MFMA attention (4 waves/block) ----------------
#define PADW 104
__global__ __launch_bounds__(256) void attn_fused(
    const ushort* __restrict__ qkv, const ushort* __restrict__ Vt,
    ushort* __restrict__ attn_out) {
    const int lane = threadIdx.x & 63;
    const int wib  = threadIdx.x >> 6;
    const int unit = blockIdx.x * 4 + wib;   // 0..2047
    const int qb = unit & 63;
    const int h  = (unit >> 6) & 15;
    const int b  = unit >> 10;
    const int qs = qb * 32;
    const int kstart = qs - 32;
    const int c15 = lane & 15, g = lane >> 4;
    const bool edge = (qb == 0) || (qb == 63);

    __shared__ ushort P_lds[4][32 * PADW];

    const ushort* Qbase = qkv + (size_t)(b * 2048 + qs) * 3072 + h * 64;

    bf16x8 qf[2][2];
#pragma unroll
    for (int qt = 0; qt < 2; ++qt)
#pragma unroll
        for (int dc = 0; dc < 2; ++dc)
            qf[qt][dc] = *reinterpret_cast<const bf16x8*>(
                Qbase + (size_t)(qt * 16 + c15) * 3072 + dc * 32 + g * 8);

    f32x4 accS[6][2] = {};
#pragma unroll
    for (int kt = 0; kt < 6; ++kt) {
        int krow = kstart + kt * 16 + c15;
        krow = min(max(krow, 0), 2047);
        const ushort* Krow = qkv + (size_t)(b * 2048 + krow) * 3072 + 1024 + h * 64;
#pragma unroll
        for (int dc = 0; dc < 2; ++dc) {
            bf16x8 kf = *reinterpret_cast<const bf16x8*>(Krow + dc * 32 + g * 8);
#pragma unroll
            for (int qt = 0; qt < 2; ++qt)
                accS[kt][qt] = __builtin_amdgcn_mfma_f32_16x16x32_bf16(
                    kf, qf[qt][dc], accS[kt][qt], 0, 0, 0);
        }
    }

    float mx[2] = {-1e30f, -1e30f};
    if (edge) {
#pragma unroll
        for (int kt = 0; kt < 6; ++kt)
#pragma unroll
            for (int qt = 0; qt < 2; ++qt)
#pragma unroll
                for (int r = 0; r < 4; ++r) {
                    const int vk = kt * 16 + g * 4 + r;
                    const int qi = qt * 16 + c15;
                    const int ki = kstart + vk;
                    const int s_row = qs + qi;
                    float val = -1e30f;
                    if (vk >= qi && vk <= qi + 63 && ki >= 0 && ki <= 2047) {
                        float bias = 0.f;
                        if (ki == 0 && s_row <= 32)
                            bias = __logf((float)(33 - s_row));
                        if (ki == 2047 && s_row >= 2016)
                            bias = __logf((float)(s_row - 2015));
                        val = accS[kt][qt][r] * 0.125f + bias;
                    }
                    accS[kt][qt][r] = val;
                    mx[qt] = fmaxf(mx[qt], val);
                }
    } else {
#pragma unroll
        for (int kt = 0; kt < 6; ++kt)
#pragma unroll
            for (int qt = 0; qt < 2; ++qt)
#pragma unroll
                for (int r = 0; r < 4; ++r) {
                    const int vk = kt * 16 + g * 4 + r;
                    const int qi = qt * 16 + c15;
                    float val = -1e30f;
                    if (vk >= qi && vk <= qi + 63)
                        val = accS[kt][qt][r] * 0.125f;
                    accS[kt][qt][r] = val;
                    mx[qt] = fmaxf(mx[qt], val);
                }
    }
#pragma unroll
    for (int qt = 0; qt < 2; ++qt) {
        mx[qt] = fmaxf(mx[qt], __shfl_xor(mx[qt], 16));
        mx[qt] = fmaxf(mx[qt], __shfl_xor(mx[qt], 32));
    }

    float sum[2] = {0.f, 0.f};
#pragma unroll
    for (int kt = 0; kt < 6; ++kt)
#pragma unroll
        for (int qt = 0; qt < 2; ++qt)
#pragma unroll
            for (int r = 0; r < 4; ++r) {
                float p = __expf(accS[kt][qt][r] - mx[qt]);
                accS[kt][qt][r] = p;
                sum[qt] += p;
            }
#pragma unroll
    for (int qt = 0; qt < 2; ++qt) {
        sum[qt] += __shfl_xor(sum[qt], 16);
        sum[qt] += __shfl_xor(sum[qt], 32);
        sum[qt] = 1.f / sum[qt];
    }

#pragma unroll
    for (int kt = 0; kt < 6; ++kt)
#pragma unroll
        for (int qt = 0; qt < 2; ++qt)
#pragma unroll
            for (int r = 0; r < 4; ++r) {
                const int vk = kt * 16 + g * 4 + r;
                const int qi = qt * 16 + c15;
                P_lds[wib][qi * PADW + vk] = f32_to_bf16_rne(accS[kt][qt][r] * sum[qt]);
            }

    const ushort* VtH = Vt + ((size_t)(b * 16 + h) * 64) * 2048;
    f32x4 accO[2][4] = {};
#pragma unroll
    for (int u = 0; u < 3; ++u) {
        bf16x8 pf[2];
#pragma unroll
        for (int qt = 0; qt < 2; ++qt)
            pf[qt] = *reinterpret_cast<const bf16x8*>(
                &P_lds[wib][(qt * 16 + c15) * PADW + u * 32 + g * 8]);
        int soff = kstart + u * 32 + g * 8;
        soff = min(max(soff, 0), 2040);
#pragma unroll
        for (int dt = 0; dt < 4; ++dt) {
            bf16x8 vf = *reinterpret_cast<const bf16x8*>(
                VtH + (size_t)(dt * 16 + c15) * 2048 + soff);
#pragma unroll
            for (int qt = 0; qt < 2; ++qt)
                accO[qt][dt] = __builtin_amdgcn_mfma_f32_16x16x32_bf16(
                    pf[qt], vf, accO[qt][dt], 0, 0, 0);
        }
    }

#pragma unroll
    for (int qt = 0; qt < 2; ++qt)
#pragma unroll
        for (int dt = 0; dt < 4; ++dt)
#pragma unroll
            for (int r = 0; r < 4; ++r) {
                const int row = b * 2048 + qs + qt * 16 + g * 4 + r;
                const int col = h * 64 + dt * 16 + c15;
                attn_out[(size_t)row * 1024 + col] = f32_to_bf16_rne(accO[qt][dt][r]);
            }
}

// ---------------- launch ----------------
extern "C" void kernel_launch(void* const* d_in, const int* in_sizes, int n_in,
                              void* d_out, int out_size, void* d_ws, size_t ws_size,
                              hipStream_t stream) {
    const float* x  = (const float*)d_in[0];
    const float* Wq = (const float*)d_in[2];
    const float* Wk = (const float*)d_in[3];
    const float* Wv = (const float*)d_in[4];
    const float* Wo = (const float*)d_in[5];
    const float* bo = (const float*)d_in[6];

    const int M = 4096;
    const int DIM = 1024;

    ushort* xb   = (ushort*)d_ws;                 // 4096*1024
    ushort* Wqkv = xb + (size_t)M * DIM;          // 3072*1024
    ushort* Wob  = Wqkv + (size_t)3072 * 1024;    // 1024*1024
    ushort* qkv  = Wob + (size_t)1024 * 1024;     // 4096*3072 (V-range unused)
    ushort* attn = qkv + (size_t)M * 3072;        // 4096*1024
    ushort* Vt   = attn + (size_t)M * DIM;        // 2*16*64*2048

    cvt_all<<<8192, 256, 0, stream>>>(
        (const float4*)x, (const float4*)Wq, (const float4*)Wk,
        (const float4*)Wv, (const float4*)Wo,
        (ushort4*)xb, (ushort4*)Wqkv, (ushort4*)Wob);

    gemm256<<<dim3(3072 / 256, M / 256), 512, 0, stream>>>(
        xb, Wqkv, qkv, Vt, M, 3072, DIM);

    attn_fused<<<512, 256, 0, stream>>>(qkv, Vt, attn);

    gemm128p<<<dim3(DIM / 128, M / 128), 256, 0, stream>>>(
        attn, Wob, (float*)d_out, bo, M, DIM, DIM);
}

// Round 7
// 73.927 us; speedup vs baseline: 2.8476x; 1.0538x over previous
//
#include <hip/hip_runtime.h>
#include <hip/hip_bf16.h>

// CantorMultiheadFusion: x -> QKV proj -> sliding-window(K=64, clipped) MHA -> out proj (+bias)
// B=2 S=2048 DIM=1024 H=16 D=64 K=64
//
// Pipeline (4 launches):
//  1) cvt_all: f32->bf16 for x, [Wq;Wk;Wv], Wo
//  2) gemm256: qkv bf16 = x @ Wqkv^T (256x256, BK=64, 8 waves, counted-vmcnt 4-phase,
//     granule-XOR swizzle, XCD-swizzled grid). V-range -> transposed store into Vt.
//  3) attn_fused: banded MFMA attention (4 waves/block, XCD-swizzled), edge clipping
//     via log-multiplicity bias
//  4) gemm_out: out f32 = attn @ Wo^T + bo (64x128 tile, 4-phase vmcnt(3), grid 512 = 2/CU)

typedef __attribute__((ext_vector_type(8))) short bf16x8;
typedef __attribute__((ext_vector_type(4))) float f32x4;

__device__ __forceinline__ unsigned short f32_to_bf16_rne(float f) {
    unsigned u = __float_as_uint(f);
    u += 0x7FFFu + ((u >> 16) & 1u);
    return (unsigned short)(u >> 16);
}
__device__ __forceinline__ float bf16_to_f32(unsigned short s) {
    return __uint_as_float(((unsigned)s) << 16);
}

#define VMCNT4 asm volatile("s_waitcnt vmcnt(4)" ::: "memory")
#define VMCNT3 asm volatile("s_waitcnt vmcnt(3)" ::: "memory")
#define VMCNT0 asm volatile("s_waitcnt vmcnt(0)" ::: "memory")
#define MEMFENCE asm volatile("" ::: "memory")

// ---------------- merged conversion kernel ----------------
__global__ __launch_bounds__(256) void cvt_all(
    const float4* __restrict__ x,
    const float4* __restrict__ Wq, const float4* __restrict__ Wk,
    const float4* __restrict__ Wv, const float4* __restrict__ Wo,
    ushort4* __restrict__ xb, ushort4* __restrict__ wqkv,
    ushort4* __restrict__ wob) {
    const int XN = (4096 * 1024) / 4;
    const int WN = (1024 * 1024) / 4;
    int i = blockIdx.x * 256 + threadIdx.x;
    float4 v;
    ushort4* dst;
    if (i < XN) {
        v = x[i];
        dst = xb + i;
    } else {
        int j = i - XN;
        int w = j >> 18;
        int k = j & (WN - 1);
        const float4* s = (w == 0) ? Wq : (w == 1) ? Wk : (w == 2) ? Wv : Wo;
        v = s[k];
        dst = (w < 3) ? (wqkv + (size_t)w * WN + k) : (wob + k);
    }
    ushort4 o;
    o.x = f32_to_bf16_rne(v.x);
    o.y = f32_to_bf16_rne(v.y);
    o.z = f32_to_bf16_rne(v.z);
    o.w = f32_to_bf16_rne(v.w);
    *dst = o;
}

// ---------------- 256x256 8-wave counted-vmcnt NT GEMM ----------------
// C[M][N] = A[M][K]*B[N][K]^T. Q/K columns -> qkv (bf16). V columns (col>=2048)
// -> transposed store into Vt[b][h][64][2048]. Flat grid 192, XCD-swizzled.
__global__ __launch_bounds__(512, 2) void gemm256(
    const ushort* __restrict__ A, const ushort* __restrict__ B,
    ushort* __restrict__ C, ushort* __restrict__ Vt, int M, int N, int K) {
    __shared__ ushort smem[65536];   // 128 KB

    const int t = threadIdx.x;
    const int l = t & 63, w = t >> 6;
    const int wm = w >> 2, wn = w & 3;     // 2 x 4 waves
    const int c15 = l & 15, g = l >> 4;
    // XCD swizzle: 192 blocks, 192 % 8 == 0 -> bijective
    const int bid = blockIdx.x;
    const int swz = (bid & 7) * 24 + (bid >> 3);
    const int mBase = (swz / 12) * 256, nBase = (swz % 12) * 256;
    const int NT = K >> 6;

    int rr[2], kk8[2];
#pragma unroll
    for (int j = 0; j < 2; ++j) {
        const int L = (w * 2 + j) * 1024 + l * 16;
        const int rp = L >> 7;
        const int glog = ((L >> 4) & 7) ^ (rp & 7);
        rr[j] = rp * 2 + (glog >> 2);
        kk8[j] = (glog & 3) * 8;
    }

    int aOff[8], bOff[4];
#pragma unroll
    for (int m8 = 0; m8 < 8; ++m8) {
        const int R = wm * 128 + m8 * 16 + c15;
        const int rp = R >> 1;
        aOff[m8] = rp * 64 + ((((R & 1) << 2) | g) ^ (rp & 7)) * 8;
    }
#pragma unroll
    for (int n4 = 0; n4 < 4; ++n4) {
        const int R = wn * 64 + n4 * 16 + c15;
        const int rp = R >> 1;
        bOff[n4] = rp * 64 + ((((R & 1) << 2) | g) ^ (rp & 7)) * 8;
    }

    f32x4 acc[8][4] = {};
    bf16x8 aF[8], bF0[2], bF1[2];

    auto stage = [&](int dbuf, int mat, int h, int kt, const ushort* Msrc, int rowBase) {
#pragma unroll
        for (int j = 0; j < 2; ++j) {
            const ushort* src = Msrc + (size_t)(rowBase + rr[j]) * K + kt * 64 + h * 32 + kk8[j];
            __builtin_amdgcn_global_load_lds(
                (const __attribute__((address_space(1))) void*)src,
                (__attribute__((address_space(3))) void*)
                    &smem[dbuf * 32768 + mat * 16384 + h * 8192 + (w * 2 + j) * 512 + l * 8],
                16, 0, 0);
        }
    };

#define LOAD_AF(CUR, KS)                                                        \
    {                                                                           \
        const int ab = (CUR) * 32768 + (KS) * 8192;                             \
        _Pragma("unroll") for (int m8 = 0; m8 < 8; ++m8)                        \
            aF[m8] = *reinterpret_cast<const bf16x8*>(&smem[ab + aOff[m8]]);    \
    }
#define LOAD_BF(DST, CUR, KS, NH)                                               \
    {                                                                           \
        const int bb = (CUR) * 32768 + 16384 + (KS) * 8192;                     \
        _Pragma("unroll") for (int n = 0; n < 2; ++n)                           \
            DST[n] = *reinterpret_cast<const bf16x8*>(&smem[bb + bOff[(NH) * 2 + n]]); \
    }
#define DO_MFMA(NH, BF)                                                         \
    __builtin_amdgcn_s_setprio(1);                                              \
    _Pragma("unroll") for (int m8 = 0; m8 < 8; ++m8) {                          \
        _Pragma("unroll") for (int n = 0; n < 2; ++n)                           \
            acc[m8][(NH) * 2 + n] = __builtin_amdgcn_mfma_f32_16x16x32_bf16(    \
                aF[m8], BF[n], acc[m8][(NH) * 2 + n], 0, 0, 0);                 \
    }                                                                           \
    __builtin_amdgcn_s_setprio(0);

    stage(0, 0, 0, 0, A, mBase);
    stage(0, 1, 0, 0, B, nBase);
    stage(0, 0, 1, 0, A, mBase);
    stage(0, 1, 1, 0, B, nBase);

    for (int kt = 0; kt < NT - 1; ++kt) {
        const int cur = kt & 1, nxt = cur ^ 1;
        VMCNT4;
        __builtin_amdgcn_s_barrier();
        MEMFENCE;
        LOAD_AF(cur, 0);
        LOAD_BF(bF0, cur, 0, 0);
        stage(nxt, 0, 0, kt + 1, A, mBase);
        DO_MFMA(0, bF0);
        LOAD_BF(bF1, cur, 0, 1);
        stage(nxt, 1, 0, kt + 1, B, nBase);
        DO_MFMA(1, bF1);
        VMCNT4;
        __builtin_amdgcn_s_barrier();
        MEMFENCE;
        LOAD_AF(cur, 1);
        LOAD_BF(bF0, cur, 1, 0);
        stage(nxt, 0, 1, kt + 1, A, mBase);
        DO_MFMA(0, bF0);
        LOAD_BF(bF1, cur, 1, 1);
        stage(nxt, 1, 1, kt + 1, B, nBase);
        DO_MFMA(1, bF1);
    }

    {
        const int cur = (NT - 1) & 1;
        VMCNT4;
        __builtin_amdgcn_s_barrier();
        MEMFENCE;
        LOAD_AF(cur, 0);
        LOAD_BF(bF0, cur, 0, 0);
        DO_MFMA(0, bF0);
        LOAD_BF(bF1, cur, 0, 1);
        DO_MFMA(1, bF1);
        VMCNT0;
        __builtin_amdgcn_s_barrier();
        MEMFENCE;
        LOAD_AF(cur, 1);
        LOAD_BF(bF0, cur, 1, 0);
        DO_MFMA(0, bF0);
        LOAD_BF(bF1, cur, 1, 1);
        DO_MFMA(1, bF1);
    }

    if (nBase < 2048) {
#pragma unroll
        for (int m8 = 0; m8 < 8; ++m8) {
#pragma unroll
            for (int n4 = 0; n4 < 4; ++n4) {
                const int col = nBase + wn * 64 + n4 * 16 + c15;
#pragma unroll
                for (int r = 0; r < 4; ++r) {
                    const int row = mBase + wm * 128 + m8 * 16 + g * 4 + r;
                    C[(size_t)row * N + col] = f32_to_bf16_rne(acc[m8][n4][r]);
                }
            }
        }
    } else {
        const int bb_ = mBase >> 11;
#pragma unroll
        for (int m8 = 0; m8 < 8; ++m8) {
            const int s0 = (mBase & 2047) + wm * 128 + m8 * 16 + g * 4;
#pragma unroll
            for (int n4 = 0; n4 < 4; ++n4) {
                const int vcol = nBase - 2048 + wn * 64 + n4 * 16 + c15;
                const int hh = vcol >> 6, dd = vcol & 63;
                ushort4 vv;
                vv.x = f32_to_bf16_rne(acc[m8][n4][0]);
                vv.y = f32_to_bf16_rne(acc[m8][n4][1]);
                vv.z = f32_to_bf16_rne(acc[m8][n4][2]);
                vv.w = f32_to_bf16_rne(acc[m8][n4][3]);
                *reinterpret_cast<ushort4*>(
                    &Vt[(((size_t)(bb_ * 16 + hh) * 64 + dd) << 11) + s0]) = vv;
            }
        }
    }
#undef LOAD_AF
#undef LOAD_BF
#undef DO_MFMA
}

// ---------------- 64x128 4-wave counted-vmcnt NT GEMM (f32 + bias out) ----------------
// Grid 512 flat (XCD-swizzled) -> 2 blocks/CU; 48 KB LDS. Per half-tile stage =
// A(1 instr) + B(2 instr) = trio -> vmcnt(3) steady state.
__global__ __launch_bounds__(256, 3) void gemm_out(
    const ushort* __restrict__ A, const ushort* __restrict__ B,
    float* __restrict__ C, const float* __restrict__ bias, int M, int N, int K) {
    __shared__ ushort smem[24576];   // 48 KB: [dbuf2][ A(2x2K us) | B(2x4K us) ]

    const int t = threadIdx.x;
    const int l = t & 63, w = t >> 6;      // 4 waves
    const int wm = w >> 1, wn = w & 1;     // 2 x 2
    const int c15 = l & 15, g = l >> 4;
    const int bid = blockIdx.x;            // 512 blocks, %8==0 -> bijective swizzle
    const int swz = (bid & 7) * 64 + (bid >> 3);
    const int mBase = (swz >> 3) * 64, nBase = (swz & 7) * 128;
    const int NT = K >> 6;

    // A staging: 1 chunk/thread (4 KB region per k-half)
    int rA_, k8A_;
    {
        const int L = w * 1024 + l * 16;
        const int rp = L >> 7;
        const int gl = ((L >> 4) & 7) ^ (rp & 7);
        rA_ = rp * 2 + (gl >> 2);
        k8A_ = (gl & 3) * 8;
    }
    // B staging: 2 chunks/thread (8 KB region per k-half)
    int rB_[2], k8B_[2];
#pragma unroll
    for (int j = 0; j < 2; ++j) {
        const int L = (w * 2 + j) * 1024 + l * 16;
        const int rp = L >> 7;
        const int gl = ((L >> 4) & 7) ^ (rp & 7);
        rB_[j] = rp * 2 + (gl >> 2);
        k8B_[j] = (gl & 3) * 8;
    }

    int aOff[2], bOff[4];
#pragma unroll
    for (int m2 = 0; m2 < 2; ++m2) {
        const int R = wm * 32 + m2 * 16 + c15;
        const int rp = R >> 1;
        aOff[m2] = rp * 64 + ((((R & 1) << 2) | g) ^ (rp & 7)) * 8;
    }
#pragma unroll
    for (int n4 = 0; n4 < 4; ++n4) {
        const int R = wn * 64 + n4 * 16 + c15;
        const int rp = R >> 1;
        bOff[n4] = rp * 64 + ((((R & 1) << 2) | g) ^ (rp & 7)) * 8;
    }

    f32x4 acc[2][4] = {};
    bf16x8 aF[2], bF0[2], bF1[2];

    // stage one k-half trio: A (1 instr) then B (2 instr)
    auto stage = [&](int dbuf, int kh, int kt) {
        const ushort* sa = A + (size_t)(mBase + rA_) * K + kt * 64 + kh * 32 + k8A_;
        __builtin_amdgcn_global_load_lds(
            (const __attribute__((address_space(1))) void*)sa,
            (__attribute__((address_space(3))) void*)
                &smem[dbuf * 12288 + kh * 2048 + w * 512 + l * 8],
            16, 0, 0);
#pragma unroll
        for (int j = 0; j < 2; ++j) {
            const ushort* sb = B + (size_t)(nBase + rB_[j]) * K + kt * 64 + kh * 32 + k8B_[j];
            __builtin_amdgcn_global_load_lds(
                (const __attribute__((address_space(1))) void*)sb,
                (__attribute__((address_space(3))) void*)
                    &smem[dbuf * 12288 + 4096 + kh * 4096 + (w * 2 + j) * 512 + l * 8],
                16, 0, 0);
        }
    };

#define LOAD_AF2(CUR, KS)                                                       \
    {                                                                           \
        const int ab = (CUR) * 12288 + (KS) * 2048;                             \
        _Pragma("unroll") for (int m2 = 0; m2 < 2; ++m2)                        \
            aF[m2] = *reinterpret_cast<const bf16x8*>(&smem[ab + aOff[m2]]);    \
    }
#define LOAD_BF2(DST, CUR, KS, NH)                                              \
    {                                                                           \
        const int bb = (CUR) * 12288 + 4096 + (KS) * 4096;                      \
        _Pragma("unroll") for (int n = 0; n < 2; ++n)                           \
            DST[n] = *reinterpret_cast<const bf16x8*>(&smem[bb + bOff[(NH) * 2 + n]]); \
    }
#define DO_MFMA2(NH, BF)                                                        \
    __builtin_amdgcn_s_setprio(1);                                              \
    _Pragma("unroll") for (int m2 = 0; m2 < 2; ++m2) {                          \
        _Pragma("unroll") for (int n = 0; n < 2; ++n)                           \
            acc[m2][(NH) * 2 + n] = __builtin_amdgcn_mfma_f32_16x16x32_bf16(    \
                aF[m2], BF[n], acc[m2][(NH) * 2 + n], 0, 0, 0);                 \
    }                                                                           \
    __builtin_amdgcn_s_setprio(0);

    stage(0, 0, 0);
    stage(0, 1, 0);

    for (int kt = 0; kt < NT - 1; ++kt) {
        const int cur = kt & 1, nxt = cur ^ 1;
        VMCNT3;                       // k0 trio landed; k1 trio may fly
        __builtin_amdgcn_s_barrier();
        MEMFENCE;
        LOAD_AF2(cur, 0);
        LOAD_BF2(bF0, cur, 0, 0);
        stage(nxt, 0, kt + 1);        // +3 -> 6 outstanding
        DO_MFMA2(0, bF0);
        LOAD_BF2(bF1, cur, 0, 1);
        DO_MFMA2(1, bF1);
        VMCNT3;                       // k1 trio landed; nxt-k0 trio flies
        __builtin_amdgcn_s_barrier();
        MEMFENCE;
        LOAD_AF2(cur, 1);
        LOAD_BF2(bF0, cur, 1, 0);
        stage(nxt, 1, kt + 1);        // +3 -> 6
        DO_MFMA2(0, bF0);
        LOAD_BF2(bF1, cur, 1, 1);
        DO_MFMA2(1, bF1);
    }

    {
        const int cur = (NT - 1) & 1;
        VMCNT3;
        __builtin_amdgcn_s_barrier();
        MEMFENCE;
        LOAD_AF2(cur, 0);
        LOAD_BF2(bF0, cur, 0, 0);
        DO_MFMA2(0, bF0);
        LOAD_BF2(bF1, cur, 0, 1);
        DO_MFMA2(1, bF1);
        VMCNT0;
        __builtin_amdgcn_s_barrier();
        MEMFENCE;
        LOAD_AF2(cur, 1);
        LOAD_BF2(bF0, cur, 1, 0);
        DO_MFMA2(0, bF0);
        LOAD_BF2(bF1, cur, 1, 1);
        DO_MFMA2(1, bF1);
    }

#pragma unroll
    for (int m2 = 0; m2 < 2; ++m2) {
#pragma unroll
        for (int n4 = 0; n4 < 4; ++n4) {
            const int col = nBase + wn * 64 + n4 * 16 + c15;
#pragma unroll
            for (int r = 0; r < 4; ++r) {
                const int row = mBase + wm * 32 + m2 * 16 + g * 4 + r;
                C[(size_t)row * N + col] = acc[m2][n4][r] + bias[col];
            }
        }
    }
#undef LOAD_AF2
#undef LOAD_BF2
#undef DO_MFMA2
}

// ---------------- unified banded MFMA attention (4 waves/block) ----------------
#define PADW 104
__global__ __launch_bounds__(256) void attn_fused(
    const ushort* __restrict__ qkv, const ushort* __restrict__ Vt,
    ushort* __restrict__ attn_out) {
    const int lane = threadIdx.x & 63;
    const int wib  = threadIdx.x >> 6;
    // XCD swizzle: 512 blocks, bijective
    const int bid = blockIdx.x;
    const int swz = (bid & 7) * 64 + (bid >> 3);
    const int unit = swz * 4 + wib;   // 0..2047
    const int qb = unit & 63;
    const int h  = (unit >> 6) & 15;
    const int b  = unit >> 10;
    const int qs = qb * 32;
    const int kstart = qs - 32;
    const int c15 = lane & 15, g = lane >> 4;
    const bool edge = (qb == 0) || (qb == 63);

    __shared__ ushort P_lds[4][32 * PADW];

    const ushort* Qbase = qkv + (size_t)(b * 2048 + qs) * 3072 + h * 64;

    bf16x8 qf[2][2];
#pragma unroll
    for (int qt = 0; qt < 2; ++qt)
#pragma unroll
        for (int dc = 0; dc < 2; ++dc)
            qf[qt][dc] = *reinterpret_cast<const bf16x8*>(
                Qbase + (size_t)(qt * 16 + c15) * 3072 + dc * 32 + g * 8);

    f32x4 accS[6][2] = {};
#pragma unroll
    for (int kt = 0; kt < 6; ++kt) {
        int krow = kstart + kt * 16 + c15;
        krow = min(max(krow, 0), 2047);
        const ushort* Krow = qkv + (size_t)(b * 2048 + krow) * 3072 + 1024 + h * 64;
#pragma unroll
        for (int dc = 0; dc < 2; ++dc) {
            bf16x8 kf = *reinterpret_cast<const bf16x8*>(Krow + dc * 32 + g * 8);
#pragma unroll
            for (int qt = 0; qt < 2; ++qt)
                accS[kt][qt] = __builtin_amdgcn_mfma_f32_16x16x32_bf16(
                    kf, qf[qt][dc], accS[kt][qt], 0, 0, 0);
        }
    }

    float mx[2] = {-1e30f, -1e30f};
    if (edge) {
#pragma unroll
        for (int kt = 0; kt < 6; ++kt)
#pragma unroll
            for (int qt = 0; qt < 2; ++qt)
#pragma unroll
                for (int r = 0; r < 4; ++r) {
                    const int vk = kt * 16 + g * 4 + r;
                    const int qi = qt * 16 + c15;
                    const int ki = kstart + vk;
                    const int s_row = qs + qi;
                    float val = -1e30f;
                    if (vk >= qi && vk <= qi + 63 && ki >= 0 && ki <= 2047) {
                        float bias = 0.f;
                        if (ki == 0 && s_row <= 32)
                            bias = __logf((float)(33 - s_row));
                        if (ki == 2047 && s_row >= 2016)
                            bias = __logf((float)(s_row - 2015));
                        val = accS[kt][qt][r] * 0.125f + bias;
                    }
                    accS[kt][qt][r] = val;
                    mx[qt] = fmaxf(mx[qt], val);
                }
    } else {
#pragma unroll
        for (int kt = 0; kt < 6; ++kt)
#pragma unroll
            for (int qt = 0; qt < 2; ++qt)
#pragma unroll
                for (int r = 0; r < 4; ++r) {
                    const int vk = kt * 16 + g * 4 + r;
                    const int qi = qt * 16 + c15;
                    float val = -1e30f;
                    if (vk >= qi && vk <= qi + 63)
                        val = accS[kt][qt][r] * 0.125f;
                    accS[kt][qt][r] = val;
                    mx[qt] = fmaxf(mx[qt], val);
                }
    }
#pragma unroll
    for (int qt = 0; qt < 2; ++qt) {
        mx[qt] = fmaxf(mx[qt], __shfl_xor(mx[qt], 16));
        mx[qt] = fmaxf(mx[qt], __shfl_xor(mx[qt], 32));
    }

    float sum[2] = {0.f, 0.f};
#pragma unroll
    for (int kt = 0; kt < 6; ++kt)
#pragma unroll
        for (int qt = 0; qt < 2; ++qt)
#pragma unroll
            for (int r = 0; r < 4; ++r) {
                float p = __expf(accS[kt][qt][r] - mx[qt]);
                accS[kt][qt][r] = p;
                sum[qt] += p;
            }
#pragma unroll
    for (int qt = 0; qt < 2; ++qt) {
        sum[qt] += __shfl_xor(sum[qt], 16);
        sum[qt] += __shfl_xor(sum[qt], 32);
        sum[qt] = 1.f / sum[qt];
    }

#pragma unroll
    for (int kt = 0; kt < 6; ++kt)
#pragma unroll
        for (int qt = 0; qt < 2; ++qt)
#pragma unroll
            for (int r = 0; r < 4; ++r) {
                const int vk = kt * 16 + g * 4 + r;
                const int qi = qt * 16 + c15;
                P_lds[wib][qi * PADW + vk] = f32_to_bf16_rne(accS[kt][qt][r] * sum[qt]);
            }

    const ushort* VtH = Vt + ((size_t)(b * 16 + h) * 64) * 2048;
    f32x4 accO[2][4] = {};
#pragma unroll
    for (int u = 0; u < 3; ++u) {
        bf16x8 pf[2];
#pragma unroll
        for (int qt = 0; qt < 2; ++qt)
            pf[qt] = *reinterpret_cast<const bf16x8*>(
                &P_lds[wib][(qt * 16 + c15) * PADW + u * 32 + g * 8]);
        int soff = kstart + u * 32 + g * 8;
        soff = min(max(soff, 0), 2040);
#pragma unroll
        for (int dt = 0; dt < 4; ++dt) {
            bf16x8 vf = *reinterpret_cast<const bf16x8*>(
                VtH + (size_t)(dt * 16 + c15) * 2048 + soff);
#pragma unroll
            for (int qt = 0; qt < 2; ++qt)
                accO[qt][dt] = __builtin_amdgcn_mfma_f32_16x16x32_bf16(
                    pf[qt], vf, accO[qt][dt], 0, 0, 0);
        }
    }

#pragma unroll
    for (int qt = 0; qt < 2; ++qt)
#pragma unroll
        for (int dt = 0; dt < 4; ++dt)
#pragma unroll
            for (int r = 0; r < 4; ++r) {
                const int row = b * 2048 + qs + qt * 16 + g * 4 + r;
                const int col = h * 64 + dt * 16 + c15;
                attn_out[(size_t)row * 1024 + col] = f32_to_bf16_rne(accO[qt][dt][r]);
            }
}

// ---------------- launch ----------------
extern "C" void kernel_launch(void* const* d_in, const int* in_sizes, int n_in,
                              void* d_out, int out_size, void* d_ws, size_t ws_size,
                              hipStream_t stream) {
    const float* x  = (const float*)d_in[0];
    const float* Wq = (const float*)d_in[2];
    const float* Wk = (const float*)d_in[3];
    const float* Wv = (const float*)d_in[4];
    const float* Wo = (const float*)d_in[5];
    const float* bo = (const float*)d_in[6];

    const int M = 4096;
    const int DIM = 1024;

    ushort* xb   = (ushort*)d_ws;                 // 4096*1024
    ushort* Wqkv = xb + (size_t)M * DIM;          // 3072*1024
    ushort* Wob  = Wqkv + (size_t)3072 * 1024;    // 1024*1024
    ushort* qkv  = Wob + (size_t)1024 * 1024;     // 4096*3072 (V-range unused)
    ushort* attn = qkv + (size_t)M * 3072;        // 4096*1024
    ushort* Vt   = attn + (size_t)M * DIM;        // 2*16*64*2048

    cvt_all<<<8192, 256, 0, stream>>>(
        (const float4*)x, (const float4*)Wq, (const float4*)Wk,
        (const float4*)Wv, (const float4*)Wo,
        (ushort4*)xb, (ushort4*)Wqkv, (ushort4*)Wob);

    gemm256<<<192, 512, 0, stream>>>(xb, Wqkv, qkv, Vt, M, 3072, DIM);

    attn_fused<<<512, 256, 0, stream>>>(qkv, Vt, attn);

    gemm_out<<<512, 256, 0, stream>>>(attn, Wob, (float*)d_out, bo, M, DIM, DIM);
}

// Round 8
// 70.762 us; speedup vs baseline: 2.9749x; 1.0447x over previous
//
#include <hip/hip_runtime.h>
#include <hip/hip_bf16.h>

// CantorMultiheadFusion: x -> QKV proj -> sliding-window(K=64, clipped) MHA -> out proj (+bias)
// B=2 S=2048 DIM=1024 H=16 D=64 K=64
//
// Pipeline (4 launches):
//  1) cvt_all: f32->bf16 for x, [Wq;Wk;Wv], Wo
//  2) gemm256: qkv bf16 = x @ Wqkv^T (256x192 tile -> grid 256 = 1 block/CU full chip,
//     BK=64, 8 waves, counted-vmcnt 2-phase/tile, granule-XOR swizzle, XCD-swizzled).
//     V-range columns -> transposed store into Vt.
//  3) attn_fused: banded MFMA attention (4 waves/block, XCD-swizzled), edge clipping
//     via log-multiplicity bias
//  4) gemm_out: out f32 = attn @ Wo^T + bo (64x128 tile, 4-phase vmcnt(3), grid 512 = 2/CU)

typedef __attribute__((ext_vector_type(8))) short bf16x8;
typedef __attribute__((ext_vector_type(4))) float f32x4;

__device__ __forceinline__ unsigned short f32_to_bf16_rne(float f) {
    unsigned u = __float_as_uint(f);
    u += 0x7FFFu + ((u >> 16) & 1u);
    return (unsigned short)(u >> 16);
}
__device__ __forceinline__ float bf16_to_f32(unsigned short s) {
    return __uint_as_float(((unsigned)s) << 16);
}

#define VMCNT4 asm volatile("s_waitcnt vmcnt(4)" ::: "memory")
#define VMCNT3 asm volatile("s_waitcnt vmcnt(3)" ::: "memory")
#define VMCNT2 asm volatile("s_waitcnt vmcnt(2)" ::: "memory")
#define VMCNT0 asm volatile("s_waitcnt vmcnt(0)" ::: "memory")
#define MEMFENCE asm volatile("" ::: "memory")

// ---------------- merged conversion kernel ----------------
__global__ __launch_bounds__(256) void cvt_all(
    const float4* __restrict__ x,
    const float4* __restrict__ Wq, const float4* __restrict__ Wk,
    const float4* __restrict__ Wv, const float4* __restrict__ Wo,
    ushort4* __restrict__ xb, ushort4* __restrict__ wqkv,
    ushort4* __restrict__ wob) {
    const int XN = (4096 * 1024) / 4;
    const int WN = (1024 * 1024) / 4;
    int i = blockIdx.x * 256 + threadIdx.x;
    float4 v;
    ushort4* dst;
    if (i < XN) {
        v = x[i];
        dst = xb + i;
    } else {
        int j = i - XN;
        int w = j >> 18;
        int k = j & (WN - 1);
        const float4* s = (w == 0) ? Wq : (w == 1) ? Wk : (w == 2) ? Wv : Wo;
        v = s[k];
        dst = (w < 3) ? (wqkv + (size_t)w * WN + k) : (wob + k);
    }
    ushort4 o;
    o.x = f32_to_bf16_rne(v.x);
    o.y = f32_to_bf16_rne(v.y);
    o.z = f32_to_bf16_rne(v.z);
    o.w = f32_to_bf16_rne(v.w);
    *dst = o;
}

// ---------------- 256x192 8-wave counted-vmcnt NT GEMM ----------------
// C[M][N] = A[M][K]*B[N][K]^T, grid 256 flat (16m x 16n), XCD-swizzled.
// LDS per dbuf (56KB): A-k0[16KB] | A-k1[16KB] | B full-K [24KB, [192][64] rows].
// Per-tile per-wave issue order [B(3), Ak0(2), Ak1(2)]:
//   ph0 vmcnt(2) -> issue B_next -> 24 MFMA(k0); ph1 vmcnt(3) -> issue A_next -> 24 MFMA(k1).
// Q/K cols -> qkv; V cols (>=2048) -> transposed store into Vt[b][h][64][2048].
__global__ __launch_bounds__(512, 2) void gemm256(
    const ushort* __restrict__ A, const ushort* __restrict__ B,
    ushort* __restrict__ C, ushort* __restrict__ Vt, int M, int N, int K) {
    __shared__ ushort smem[57344];   // 112 KB

    const int t = threadIdx.x;
    const int l = t & 63, w = t >> 6;
    const int wm = w >> 2, wn = w & 3;     // 2 x 4 waves -> wave tile 128 x 48
    const int c15 = l & 15, g = l >> 4;
    // XCD swizzle: 256 blocks, bijective
    const int bid = blockIdx.x;
    const int swz = (bid & 7) * 32 + (bid >> 3);
    const int mBase = (swz >> 4) * 256, nBase = (swz & 15) * 192;
    const int NT = K >> 6;

    // A staging geometry (2 chunks, 16KB region of [256 rows][32 k], row-pair swizzle)
    int rrA[2], k8A[2];
#pragma unroll
    for (int j = 0; j < 2; ++j) {
        const int L = (w * 2 + j) * 1024 + l * 16;
        const int rp = L >> 7;
        const int gl = ((L >> 4) & 7) ^ (rp & 7);
        rrA[j] = rp * 2 + (gl >> 2);
        k8A[j] = (gl & 3) * 8;
    }
    // B staging geometry (3 chunks, 24KB region of [192 rows][64 k], row swizzle)
    int rrB[3], k8B[3];
#pragma unroll
    for (int c = 0; c < 3; ++c) {
        const int G = c * 512 + w * 64 + l;    // granule index
        const int row = G >> 3;
        rrB[c] = row;
        k8B[c] = ((G & 7) ^ (row & 7)) * 8;
    }

    // fragment read offsets (ushort units)
    int aOff[8], bOff0[3], bOff1[3];
#pragma unroll
    for (int m8 = 0; m8 < 8; ++m8) {
        const int R = wm * 128 + m8 * 16 + c15;
        const int rp = R >> 1;
        aOff[m8] = rp * 64 + ((((R & 1) << 2) | g) ^ (rp & 7)) * 8;
    }
#pragma unroll
    for (int n3 = 0; n3 < 3; ++n3) {
        const int R = wn * 48 + n3 * 16 + c15;
        bOff0[n3] = R * 64 + ((g) ^ (R & 7)) * 8;
        bOff1[n3] = R * 64 + ((4 | g) ^ (R & 7)) * 8;
    }

    f32x4 acc[8][3] = {};
    bf16x8 aF[8], bF[3];

    auto stageA = [&](int dbuf, int kh, int kt) {
#pragma unroll
        for (int j = 0; j < 2; ++j) {
            const ushort* src = A + (size_t)(mBase + rrA[j]) * K + kt * 64 + kh * 32 + k8A[j];
            __builtin_amdgcn_global_load_lds(
                (const __attribute__((address_space(1))) void*)src,
                (__attribute__((address_space(3))) void*)
                    &smem[dbuf * 28672 + kh * 8192 + (w * 2 + j) * 512 + l * 8],
                16, 0, 0);
        }
    };
    auto stageB = [&](int dbuf, int kt) {
#pragma unroll
        for (int c = 0; c < 3; ++c) {
            const ushort* src = B + (size_t)(nBase + rrB[c]) * K + kt * 64 + k8B[c];
            __builtin_amdgcn_global_load_lds(
                (const __attribute__((address_space(1))) void*)src,
                (__attribute__((address_space(3))) void*)
                    &smem[dbuf * 28672 + 16384 + c * 4096 + w * 512 + l * 8],
                16, 0, 0);
        }
    };

#define LOAD_AF(CUR, KH)                                                        \
    {                                                                           \
        const int ab = (CUR) * 28672 + (KH) * 8192;                             \
        _Pragma("unroll") for (int m8 = 0; m8 < 8; ++m8)                        \
            aF[m8] = *reinterpret_cast<const bf16x8*>(&smem[ab + aOff[m8]]);    \
    }
#define LOAD_BF(CUR, KH)                                                        \
    {                                                                           \
        const int bb = (CUR) * 28672 + 16384;                                   \
        _Pragma("unroll") for (int n = 0; n < 3; ++n)                           \
            bF[n] = *reinterpret_cast<const bf16x8*>(                           \
                &smem[bb + ((KH) ? bOff1[n] : bOff0[n])]);                      \
    }
#define DO_MFMA()                                                               \
    __builtin_amdgcn_s_setprio(1);                                              \
    _Pragma("unroll") for (int m8 = 0; m8 < 8; ++m8) {                          \
        _Pragma("unroll") for (int n = 0; n < 3; ++n)                           \
            acc[m8][n] = __builtin_amdgcn_mfma_f32_16x16x32_bf16(               \
                aF[m8], bF[n], acc[m8][n], 0, 0, 0);                            \
    }                                                                           \
    __builtin_amdgcn_s_setprio(0);

    // prologue: per-wave issue order [B(3), Ak0(2), Ak1(2)]
    stageB(0, 0);
    stageA(0, 0, 0);
    stageA(0, 1, 0);

    for (int kt = 0; kt < NT - 1; ++kt) {
        const int cur = kt & 1, nxt = cur ^ 1;
        // ph0: need B_t + Ak0_t (oldest 5 of 7) -> leave Ak1_t
        VMCNT2;
        __builtin_amdgcn_s_barrier();
        MEMFENCE;
        LOAD_AF(cur, 0);
        LOAD_BF(cur, 0);
        stageB(nxt, kt + 1);          // outstanding: Ak1_t(2) + B_next(3)
        DO_MFMA();
        // ph1: need Ak1_t -> leave B_next(3)
        VMCNT3;
        __builtin_amdgcn_s_barrier();
        MEMFENCE;
        LOAD_AF(cur, 1);
        LOAD_BF(cur, 1);
        stageA(nxt, 0, kt + 1);
        stageA(nxt, 1, kt + 1);       // outstanding: B_next(3) + A_next(4)
        DO_MFMA();
    }

    // tail tile (no staging)
    {
        const int cur = (NT - 1) & 1;
        VMCNT2;
        __builtin_amdgcn_s_barrier();
        MEMFENCE;
        LOAD_AF(cur, 0);
        LOAD_BF(cur, 0);
        DO_MFMA();
        VMCNT0;
        __builtin_amdgcn_s_barrier();
        MEMFENCE;
        LOAD_AF(cur, 1);
        LOAD_BF(cur, 1);
        DO_MFMA();
    }

    // epilogue: per-fragment qkv vs Vt routing (2048 boundary is 16-aligned)
    const int bb_ = mBase >> 11;
#pragma unroll
    for (int m8 = 0; m8 < 8; ++m8) {
        const int row = mBase + wm * 128 + m8 * 16 + g * 4;
        const int s0 = (mBase & 2047) + wm * 128 + m8 * 16 + g * 4;
#pragma unroll
        for (int n3 = 0; n3 < 3; ++n3) {
            const int col = nBase + wn * 48 + n3 * 16 + c15;
            if (col < 2048) {
#pragma unroll
                for (int r = 0; r < 4; ++r)
                    C[(size_t)(row + r) * N + col] = f32_to_bf16_rne(acc[m8][n3][r]);
            } else {
                const int vcol = col - 2048;
                const int hh = vcol >> 6, dd = vcol & 63;
                ushort4 vv;
                vv.x = f32_to_bf16_rne(acc[m8][n3][0]);
                vv.y = f32_to_bf16_rne(acc[m8][n3][1]);
                vv.z = f32_to_bf16_rne(acc[m8][n3][2]);
                vv.w = f32_to_bf16_rne(acc[m8][n3][3]);
                *reinterpret_cast<ushort4*>(
                    &Vt[(((size_t)(bb_ * 16 + hh) * 64 + dd) << 11) + s0]) = vv;
            }
        }
    }
#undef LOAD_AF
#undef LOAD_BF
#undef DO_MFMA
}

// ---------------- 64x128 4-wave counted-vmcnt NT GEMM (f32 + bias out) ----------------
__global__ __launch_bounds__(256, 3) void gemm_out(
    const ushort* __restrict__ A, const ushort* __restrict__ B,
    float* __restrict__ C, const float* __restrict__ bias, int M, int N, int K) {
    __shared__ ushort smem[24576];   // 48 KB

    const int t = threadIdx.x;
    const int l = t & 63, w = t >> 6;      // 4 waves
    const int wm = w >> 1, wn = w & 1;     // 2 x 2
    const int c15 = l & 15, g = l >> 4;
    const int bid = blockIdx.x;            // 512 blocks
    const int swz = (bid & 7) * 64 + (bid >> 3);
    const int mBase = (swz >> 3) * 64, nBase = (swz & 7) * 128;
    const int NT = K >> 6;

    int rA_, k8A_;
    {
        const int L = w * 1024 + l * 16;
        const int rp = L >> 7;
        const int gl = ((L >> 4) & 7) ^ (rp & 7);
        rA_ = rp * 2 + (gl >> 2);
        k8A_ = (gl & 3) * 8;
    }
    int rB_[2], k8B_[2];
#pragma unroll
    for (int j = 0; j < 2; ++j) {
        const int L = (w * 2 + j) * 1024 + l * 16;
        const int rp = L >> 7;
        const int gl = ((L >> 4) & 7) ^ (rp & 7);
        rB_[j] = rp * 2 + (gl >> 2);
        k8B_[j] = (gl & 3) * 8;
    }

    int aOff[2], bOff[4];
#pragma unroll
    for (int m2 = 0; m2 < 2; ++m2) {
        const int R = wm * 32 + m2 * 16 + c15;
        const int rp = R >> 1;
        aOff[m2] = rp * 64 + ((((R & 1) << 2) | g) ^ (rp & 7)) * 8;
    }
#pragma unroll
    for (int n4 = 0; n4 < 4; ++n4) {
        const int R = wn * 64 + n4 * 16 + c15;
        const int rp = R >> 1;
        bOff[n4] = rp * 64 + ((((R & 1) << 2) | g) ^ (rp & 7)) * 8;
    }

    f32x4 acc[2][4] = {};
    bf16x8 aF[2], bF0[2], bF1[2];

    auto stage = [&](int dbuf, int kh, int kt) {
        const ushort* sa = A + (size_t)(mBase + rA_) * K + kt * 64 + kh * 32 + k8A_;
        __builtin_amdgcn_global_load_lds(
            (const __attribute__((address_space(1))) void*)sa,
            (__attribute__((address_space(3))) void*)
                &smem[dbuf * 12288 + kh * 2048 + w * 512 + l * 8],
            16, 0, 0);
#pragma unroll
        for (int j = 0; j < 2; ++j) {
            const ushort* sb = B + (size_t)(nBase + rB_[j]) * K + kt * 64 + kh * 32 + k8B_[j];
            __builtin_amdgcn_global_load_lds(
                (const __attribute__((address_space(1))) void*)sb,
                (__attribute__((address_space(3))) void*)
                    &smem[dbuf * 12288 + 4096 + kh * 4096 + (w * 2 + j) * 512 + l * 8],
                16, 0, 0);
        }
    };

#define LOAD_AF2(CUR, KS)                                                       \
    {                                                                           \
        const int ab = (CUR) * 12288 + (KS) * 2048;                             \
        _Pragma("unroll") for (int m2 = 0; m2 < 2; ++m2)                        \
            aF[m2] = *reinterpret_cast<const bf16x8*>(&smem[ab + aOff[m2]]);    \
    }
#define LOAD_BF2(DST, CUR, KS, NH)                                              \
    {                                                                           \
        const int bb = (CUR) * 12288 + 4096 + (KS) * 4096;                      \
        _Pragma("unroll") for (int n = 0; n < 2; ++n)                           \
            DST[n] = *reinterpret_cast<const bf16x8*>(&smem[bb + bOff[(NH) * 2 + n]]); \
    }
#define DO_MFMA2(NH, BF)                                                        \
    __builtin_amdgcn_s_setprio(1);                                              \
    _Pragma("unroll") for (int m2 = 0; m2 < 2; ++m2) {                          \
        _Pragma("unroll") for (int n = 0; n < 2; ++n)                           \
            acc[m2][(NH) * 2 + n] = __builtin_amdgcn_mfma_f32_16x16x32_bf16(    \
                aF[m2], BF[n], acc[m2][(NH) * 2 + n], 0, 0, 0);                 \
    }                                                                           \
    __builtin_amdgcn_s_setprio(0);

    stage(0, 0, 0);
    stage(0, 1, 0);

    for (int kt = 0; kt < NT - 1; ++kt) {
        const int cur = kt & 1, nxt = cur ^ 1;
        VMCNT3;
        __builtin_amdgcn_s_barrier();
        MEMFENCE;
        LOAD_AF2(cur, 0);
        LOAD_BF2(bF0, cur, 0, 0);
        stage(nxt, 0, kt + 1);
        DO_MFMA2(0, bF0);
        LOAD_BF2(bF1, cur, 0, 1);
        DO_MFMA2(1, bF1);
        VMCNT3;
        __builtin_amdgcn_s_barrier();
        MEMFENCE;
        LOAD_AF2(cur, 1);
        LOAD_BF2(bF0, cur, 1, 0);
        stage(nxt, 1, kt + 1);
        DO_MFMA2(0, bF0);
        LOAD_BF2(bF1, cur, 1, 1);
        DO_MFMA2(1, bF1);
    }

    {
        const int cur = (NT - 1) & 1;
        VMCNT3;
        __builtin_amdgcn_s_barrier();
        MEMFENCE;
        LOAD_AF2(cur, 0);
        LOAD_BF2(bF0, cur, 0, 0);
        DO_MFMA2(0, bF0);
        LOAD_BF2(bF1, cur, 0, 1);
        DO_MFMA2(1, bF1);
        VMCNT0;
        __builtin_amdgcn_s_barrier();
        MEMFENCE;
        LOAD_AF2(cur, 1);
        LOAD_BF2(bF0, cur, 1, 0);
        DO_MFMA2(0, bF0);
        LOAD_BF2(bF1, cur, 1, 1);
        DO_MFMA2(1, bF1);
    }

#pragma unroll
    for (int m2 = 0; m2 < 2; ++m2) {
#pragma unroll
        for (int n4 = 0; n4 < 4; ++n4) {
            const int col = nBase + wn * 64 + n4 * 16 + c15;
#pragma unroll
            for (int r = 0; r < 4; ++r) {
                const int row = mBase + wm * 32 + m2 * 16 + g * 4 + r;
                C[(size_t)row * N + col] = acc[m2][n4][r] + bias[col];
            }
        }
    }
#undef LOAD_AF2
#undef LOAD_BF2
#undef DO_MFMA2
}

// ---------------- unified banded MFMA attention (4 waves/block) ----------------
#define PADW 104
__global__ __launch_bounds__(256) void attn_fused(
    const ushort* __restrict__ qkv, const ushort* __restrict__ Vt,
    ushort* __restrict__ attn_out) {
    const int lane = threadIdx.x & 63;
    const int wib  = threadIdx.x >> 6;
    const int bid = blockIdx.x;
    const int swz = (bid & 7) * 64 + (bid >> 3);
    const int unit = swz * 4 + wib;   // 0..2047
    const int qb = unit & 63;
    const int h  = (unit >> 6) & 15;
    const int b  = unit >> 10;
    const int qs = qb * 32;
    const int kstart = qs - 32;
    const int c15 = lane & 15, g = lane >> 4;
    const bool edge = (qb == 0) || (qb == 63);

    __shared__ ushort P_lds[4][32 * PADW];

    const ushort* Qbase = qkv + (size_t)(b * 2048 + qs) * 3072 + h * 64;

    bf16x8 qf[2][2];
#pragma unroll
    for (int qt = 0; qt < 2; ++qt)
#pragma unroll
        for (int dc = 0; dc < 2; ++dc)
            qf[qt][dc] = *reinterpret_cast<const bf16x8*>(
                Qbase + (size_t)(qt * 16 + c15) * 3072 + dc * 32 + g * 8);

    f32x4 accS[6][2] = {};
#pragma unroll
    for (int kt = 0; kt < 6; ++kt) {
        int krow = kstart + kt * 16 + c15;
        krow = min(max(krow, 0), 2047);
        const ushort* Krow = qkv + (size_t)(b * 2048 + krow) * 3072 + 1024 + h * 64;
#pragma unroll
        for (int dc = 0; dc < 2; ++dc) {
            bf16x8 kf = *reinterpret_cast<const bf16x8*>(Krow + dc * 32 + g * 8);
#pragma unroll
            for (int qt = 0; qt < 2; ++qt)
                accS[kt][qt] = __builtin_amdgcn_mfma_f32_16x16x32_bf16(
                    kf, qf[qt][dc], accS[kt][qt], 0, 0, 0);
        }
    }

    float mx[2] = {-1e30f, -1e30f};
    if (edge) {
#pragma unroll
        for (int kt = 0; kt < 6; ++kt)
#pragma unroll
            for (int qt = 0; qt < 2; ++qt)
#pragma unroll
                for (int r = 0; r < 4; ++r) {
                    const int vk = kt * 16 + g * 4 + r;
                    const int qi = qt * 16 + c15;
                    const int ki = kstart + vk;
                    const int s_row = qs + qi;
                    float val = -1e30f;
                    if (vk >= qi && vk <= qi + 63 && ki >= 0 && ki <= 2047) {
                        float bias = 0.f;
                        if (ki == 0 && s_row <= 32)
                            bias = __logf((float)(33 - s_row));
                        if (ki == 2047 && s_row >= 2016)
                            bias = __logf((float)(s_row - 2015));
                        val = accS[kt][qt][r] * 0.125f + bias;
                    }
                    accS[kt][qt][r] = val;
                    mx[qt] = fmaxf(mx[qt], val);
                }
    } else {
#pragma unroll
        for (int kt = 0; kt < 6; ++kt)
#pragma unroll
            for (int qt = 0; qt < 2; ++qt)
#pragma unroll
                for (int r = 0; r < 4; ++r) {
                    const int vk = kt * 16 + g * 4 + r;
                    const int qi = qt * 16 + c15;
                    float val = -1e30f;
                    if (vk >= qi && vk <= qi + 63)
                        val = accS[kt][qt][r] * 0.125f;
                    accS[kt][qt][r] = val;
                    mx[qt] = fmaxf(mx[qt], val);
                }
    }
#pragma unroll
    for (int qt = 0; qt < 2; ++qt) {
        mx[qt] = fmaxf(mx[qt], __shfl_xor(mx[qt], 16));
        mx[qt] = fmaxf(mx[qt], __shfl_xor(mx[qt], 32));
    }

    float sum[2] = {0.f, 0.f};
#pragma unroll
    for (int kt = 0; kt < 6; ++kt)
#pragma unroll
        for (int qt = 0; qt < 2; ++qt)
#pragma unroll
            for (int r = 0; r < 4; ++r) {
                float p = __expf(accS[kt][qt][r] - mx[qt]);
                accS[kt][qt][r] = p;
                sum[qt] += p;
            }
#pragma unroll
    for (int qt = 0; qt < 2; ++qt) {
        sum[qt] += __shfl_xor(sum[qt], 16);
        sum[qt] += __shfl_xor(sum[qt], 32);
        sum[qt] = 1.f / sum[qt];
    }

#pragma unroll
    for (int kt = 0; kt < 6; ++kt)
#pragma unroll
        for (int qt = 0; qt < 2; ++qt)
#pragma unroll
            for (int r = 0; r < 4; ++r) {
                const int vk = kt * 16 + g * 4 + r;
                const int qi = qt * 16 + c15;
                P_lds[wib][qi * PADW + vk] = f32_to_bf16_rne(accS[kt][qt][r] * sum[qt]);
            }

    const ushort* VtH = Vt + ((size_t)(b * 16 + h) * 64) * 2048;
    f32x4 accO[2][4] = {};
#pragma unroll
    for (int u = 0; u < 3; ++u) {
        bf16x8 pf[2];
#pragma unroll
        for (int qt = 0; qt < 2; ++qt)
            pf[qt] = *reinterpret_cast<const bf16x8*>(
                &P_lds[wib][(qt * 16 + c15) * PADW + u * 32 + g * 8]);
        int soff = kstart + u * 32 + g * 8;
        soff = min(max(soff, 0), 2040);
#pragma unroll
        for (int dt = 0; dt < 4; ++dt) {
            bf16x8 vf = *reinterpret_cast<const bf16x8*>(
                VtH + (size_t)(dt * 16 + c15) * 2048 + soff);
#pragma unroll
            for (int qt = 0; qt < 2; ++qt)
                accO[qt][dt] = __builtin_amdgcn_mfma_f32_16x16x32_bf16(
                    pf[qt], vf, accO[qt][dt], 0, 0, 0);
        }
    }

#pragma unroll
    for (int qt = 0; qt < 2; ++qt)
#pragma unroll
        for (int dt = 0; dt < 4; ++dt)
#pragma unroll
            for (int r = 0; r < 4; ++r) {
                const int row = b * 2048 + qs + qt * 16 + g * 4 + r;
                const int col = h * 64 + dt * 16 + c15;
                attn_out[(size_t)row * 1024 + col] = f32_to_bf16_rne(accO[qt][dt][r]);
            }
}

// ---------------- launch ----------------
extern "C" void kernel_launch(void* const* d_in, const int* in_sizes, int n_in,
                              void* d_out, int out_size, void* d_ws, size_t ws_size,
                              hipStream_t stream) {
    const float* x  = (const float*)d_in[0];
    const float* Wq = (const float*)d_in[2];
    const float* Wk = (const float*)d_in[3];
    const float* Wv = (const float*)d_in[4];
    const float* Wo = (const float*)d_in[5];
    const float* bo = (const float*)d_in[6];

    const int M = 4096;
    const int DIM = 1024;

    ushort* xb   = (ushort*)d_ws;                 // 4096*1024
    ushort* Wqkv = xb + (size_t)M * DIM;          // 3072*1024
    ushort* Wob  = Wqkv + (size_t)3072 * 1024;    // 1024*1024
    ushort* qkv  = Wob + (size_t)1024 * 1024;     // 4096*3072 (V-range unused)
    ushort* attn = qkv + (size_t)M * 3072;        // 4096*1024
    ushort* Vt   = attn + (size_t)M * DIM;        // 2*16*64*2048

    cvt_all<<<8192, 256, 0, stream>>>(
        (const float4*)x, (const float4*)Wq, (const float4*)Wk,
        (const float4*)Wv, (const float4*)Wo,
        (ushort4*)xb, (ushort4*)Wqkv, (ushort4*)Wob);

    gemm256<<<256, 512, 0, stream>>>(xb, Wqkv, qkv, Vt, M, 3072, DIM);

    attn_fused<<<512, 256, 0, stream>>>(qkv, Vt, attn);

    gemm_out<<<512, 256, 0, stream>>>(attn, Wob, (float*)d_out, bo, M, DIM, DIM);
}